// Round 3
// 533.957 us; speedup vs baseline: 1.0227x; 1.0227x over previous
//
#include <hip/hip_runtime.h>
#include <math.h>

#define F_IN 128
#define HID  128
#define CDIM 64
#define BN_EPS 1e-5f
#define SCAN_CHUNK 1024   // elements per scan block (256 thr x 4)

typedef unsigned int u32;
typedef unsigned short u16;

// bf16 helpers (RNE)
__device__ __forceinline__ float bf_lo(u32 p) {
    u32 x = p << 16; return __builtin_bit_cast(float, x);
}
__device__ __forceinline__ float bf_hi(u32 p) {
    u32 x = p & 0xffff0000u; return __builtin_bit_cast(float, x);
}
__device__ __forceinline__ u16 f2bf(float f) {
    u32 x = __builtin_bit_cast(u32, f);
    return (u16)((x + 0x7fffu + ((x >> 16) & 1u)) >> 16);
}
__device__ __forceinline__ u32 pack2(float a, float b) {
    return (u32)f2bf(a) | ((u32)f2bf(b) << 16);   // lo = even col
}

// ---------------------------------------------------------------------------
// GEMM1: Y[N,128](bf16) = X[N,128](fp32) @ W[128,128](fp32).
// ---------------------------------------------------------------------------
__global__ __launch_bounds__(256) void gemm_xw1(const float* __restrict__ X,
                                                const float* __restrict__ W,
                                                u32* __restrict__ Yb, int N) {
    __shared__ float Wl[64][128];    // 32 KB
    __shared__ float xs[128][64];    // 32 KB
    const int cg = (threadIdx.x & 15) * 8;
    const int rg = (threadIdx.x >> 4) * 8;
    const int ntiles = (N + 127) >> 7;
    for (int tile = blockIdx.x; tile < ntiles; tile += gridDim.x) {
        const int row0 = tile << 7;
        float acc[8][8];
        #pragma unroll
        for (int i = 0; i < 8; ++i)
            #pragma unroll
            for (int j = 0; j < 8; ++j) acc[i][j] = 0.f;

        for (int kc = 0; kc < 128; kc += 64) {
            __syncthreads();
            for (int i = threadIdx.x; i < 2048; i += 256) {
                int kr = i >> 5, c = (i & 31) * 4;
                *(float4*)&Wl[kr][c] = *(const float4*)&W[(size_t)(kc + kr) * HID + c];
            }
            for (int i = threadIdx.x; i < 2048; i += 256) {
                int r = i >> 4, c = (i & 15) * 4;
                int gr = row0 + r;
                float4 v = make_float4(0.f, 0.f, 0.f, 0.f);
                if (gr < N) v = *(const float4*)&X[(size_t)gr * F_IN + kc + c];
                *(float4*)&xs[r][c] = v;
            }
            __syncthreads();
            #pragma unroll 2
            for (int k = 0; k < 64; k += 2) {
                float2 a[8];
                #pragma unroll
                for (int i = 0; i < 8; ++i) a[i] = *(float2*)&xs[rg + i][k];
                float4 b00 = *(float4*)&Wl[k][cg];
                float4 b01 = *(float4*)&Wl[k][cg + 4];
                float4 b10 = *(float4*)&Wl[k + 1][cg];
                float4 b11 = *(float4*)&Wl[k + 1][cg + 4];
                #pragma unroll
                for (int i = 0; i < 8; ++i) {
                    acc[i][0] = fmaf(a[i].x, b00.x, acc[i][0]);
                    acc[i][1] = fmaf(a[i].x, b00.y, acc[i][1]);
                    acc[i][2] = fmaf(a[i].x, b00.z, acc[i][2]);
                    acc[i][3] = fmaf(a[i].x, b00.w, acc[i][3]);
                    acc[i][4] = fmaf(a[i].x, b01.x, acc[i][4]);
                    acc[i][5] = fmaf(a[i].x, b01.y, acc[i][5]);
                    acc[i][6] = fmaf(a[i].x, b01.z, acc[i][6]);
                    acc[i][7] = fmaf(a[i].x, b01.w, acc[i][7]);
                    acc[i][0] = fmaf(a[i].y, b10.x, acc[i][0]);
                    acc[i][1] = fmaf(a[i].y, b10.y, acc[i][1]);
                    acc[i][2] = fmaf(a[i].y, b10.z, acc[i][2]);
                    acc[i][3] = fmaf(a[i].y, b10.w, acc[i][3]);
                    acc[i][4] = fmaf(a[i].y, b11.x, acc[i][4]);
                    acc[i][5] = fmaf(a[i].y, b11.y, acc[i][5]);
                    acc[i][6] = fmaf(a[i].y, b11.z, acc[i][6]);
                    acc[i][7] = fmaf(a[i].y, b11.w, acc[i][7]);
                }
            }
        }
        #pragma unroll
        for (int i = 0; i < 8; ++i) {
            int gr = row0 + rg + i;
            if (gr < N) {
                uint4 o;
                o.x = pack2(acc[i][0], acc[i][1]);
                o.y = pack2(acc[i][2], acc[i][3]);
                o.z = pack2(acc[i][4], acc[i][5]);
                o.w = pack2(acc[i][6], acc[i][7]);
                *(uint4*)&Yb[(size_t)gr * 64 + (cg >> 1)] = o;
            }
        }
    }
}

// ---------------------------------------------------------------------------
// GEMM2: Y[N,64](bf16) = H[N,128](bf16) @ W[128,64](fp32).
// ---------------------------------------------------------------------------
__global__ __launch_bounds__(256) void gemm_xw2(const u32* __restrict__ Hb,
                                                const float* __restrict__ W,
                                                u32* __restrict__ Yb, int N) {
    __shared__ float Wl[64][64];     // 16 KB
    __shared__ float xs[128][64];    // 32 KB
    const int cg = (threadIdx.x & 15) * 4;
    const int rg = (threadIdx.x >> 4) * 8;
    const int ntiles = (N + 127) >> 7;
    for (int tile = blockIdx.x; tile < ntiles; tile += gridDim.x) {
        const int row0 = tile << 7;
        float acc[8][4];
        #pragma unroll
        for (int i = 0; i < 8; ++i)
            #pragma unroll
            for (int j = 0; j < 4; ++j) acc[i][j] = 0.f;

        for (int kc = 0; kc < 128; kc += 64) {
            __syncthreads();
            for (int i = threadIdx.x; i < 1024; i += 256) {          // W chunk
                int kr = i >> 4, c = (i & 15) * 4;
                *(float4*)&Wl[kr][c] = *(const float4*)&W[(size_t)(kc + kr) * CDIM + c];
            }
            for (int i = threadIdx.x; i < 2048; i += 256) {          // H chunk
                int r = i >> 4, uc = (i & 15) * 2;
                int gr = row0 + r;
                float4 v = make_float4(0.f, 0.f, 0.f, 0.f);
                if (gr < N) {
                    uint2 p = *(const uint2*)&Hb[(size_t)gr * 64 + (kc >> 1) + uc];
                    v = make_float4(bf_lo(p.x), bf_hi(p.x), bf_lo(p.y), bf_hi(p.y));
                }
                *(float4*)&xs[r][uc * 2] = v;
            }
            __syncthreads();
            #pragma unroll 2
            for (int k = 0; k < 64; k += 2) {
                float2 a[8];
                #pragma unroll
                for (int i = 0; i < 8; ++i) a[i] = *(float2*)&xs[rg + i][k];
                float4 b0 = *(float4*)&Wl[k][cg];
                float4 b1 = *(float4*)&Wl[k + 1][cg];
                #pragma unroll
                for (int i = 0; i < 8; ++i) {
                    acc[i][0] = fmaf(a[i].x, b0.x, acc[i][0]);
                    acc[i][1] = fmaf(a[i].x, b0.y, acc[i][1]);
                    acc[i][2] = fmaf(a[i].x, b0.z, acc[i][2]);
                    acc[i][3] = fmaf(a[i].x, b0.w, acc[i][3]);
                    acc[i][0] = fmaf(a[i].y, b1.x, acc[i][0]);
                    acc[i][1] = fmaf(a[i].y, b1.y, acc[i][1]);
                    acc[i][2] = fmaf(a[i].y, b1.z, acc[i][2]);
                    acc[i][3] = fmaf(a[i].y, b1.w, acc[i][3]);
                }
            }
        }
        #pragma unroll
        for (int i = 0; i < 8; ++i) {
            int gr = row0 + rg + i;
            if (gr < N) {
                uint2 o;
                o.x = pack2(acc[i][0], acc[i][1]);
                o.y = pack2(acc[i][2], acc[i][3]);
                *(uint2*)&Yb[(size_t)gr * 32 + (cg >> 1)] = o;
            }
        }
    }
}

// ---------------------------------------------------------------------------
// CSR build: histogram -> scan -> fill
// ---------------------------------------------------------------------------
__global__ __launch_bounds__(256) void hist_kernel(const int* __restrict__ dst,
                                                   int* __restrict__ counts, int E) {
    int gid = blockIdx.x * 256 + threadIdx.x;
    int stride = gridDim.x * 256;
    for (; gid < E; gid += stride) atomicAdd(&counts[dst[gid]], 1);
}

__global__ __launch_bounds__(256) void scan_sums(const int* __restrict__ counts,
                                                 int* __restrict__ bsums, int N) {
    __shared__ int sdata[256];
    int base = blockIdx.x * SCAN_CHUNK + threadIdx.x * 4;
    int t = 0;
    #pragma unroll
    for (int j = 0; j < 4; ++j) { int i = base + j; if (i < N) t += counts[i]; }
    sdata[threadIdx.x] = t; __syncthreads();
    for (int off = 128; off > 0; off >>= 1) {
        if (threadIdx.x < off) sdata[threadIdx.x] += sdata[threadIdx.x + off];
        __syncthreads();
    }
    if (threadIdx.x == 0) bsums[blockIdx.x] = sdata[0];
}

__global__ void scan_offsets(const int* __restrict__ bsums, int* __restrict__ boffs,
                             int nb, int* __restrict__ row_ptr, int N, int E) {
    if (threadIdx.x == 0 && blockIdx.x == 0) {
        int run = 0;
        for (int i = 0; i < nb; ++i) { boffs[i] = run; run += bsums[i]; }
        row_ptr[N] = E;
    }
}

__global__ __launch_bounds__(256) void scan_write(const int* __restrict__ counts,
                                                  const int* __restrict__ boffs,
                                                  int* __restrict__ row_ptr,
                                                  int* __restrict__ cursor, int N) {
    __shared__ int sdata[256];
    int base = blockIdx.x * SCAN_CHUNK + threadIdx.x * 4;
    int v[4]; int tsum = 0;
    #pragma unroll
    for (int j = 0; j < 4; ++j) {
        int i = base + j;
        v[j] = (i < N) ? counts[i] : 0;
        tsum += v[j];
    }
    sdata[threadIdx.x] = tsum; __syncthreads();
    for (int off = 1; off < 256; off <<= 1) {
        int t = (threadIdx.x >= off) ? sdata[threadIdx.x - off] : 0;
        __syncthreads();
        sdata[threadIdx.x] += t;
        __syncthreads();
    }
    int off0 = sdata[threadIdx.x] - tsum + boffs[blockIdx.x];
    #pragma unroll
    for (int j = 0; j < 4; ++j) {
        int i = base + j;
        if (i < N) { row_ptr[i] = off0; cursor[i] = off0; off0 += v[j]; }
    }
}

// ---------------------------------------------------------------------------
// fill: dst-sliced, XCD-aware. blockIdx.x & 7 selects a contiguous dst slice
// (1/8 of N). Since CSR order is dst-major, each slice's es_packed target
// region is a contiguous ~E/8*8B window that fits a single XCD's 4 MB L2 —
// the 8B scattered stores coalesce into full 64B lines in L2 and write back
// once (vs 8x amplification when all XCDs scatter over the whole array).
// blockIdx round-robins across the 8 XCDs, so slice s stays on one XCD
// (perf heuristic only; correctness holds for any WG->XCD mapping).
// ---------------------------------------------------------------------------
__global__ __launch_bounds__(256) void fill_kernel(const int* __restrict__ src,
                                                   const int* __restrict__ dst,
                                                   const float* __restrict__ w,
                                                   int* __restrict__ cursor,
                                                   uint2* __restrict__ es_packed,
                                                   int E, int N) {
    const int slice = blockIdx.x & 7;
    const int sw = (N + 7) >> 3;
    const int lo = slice * sw;
    const int hi = (lo + sw < N) ? (lo + sw) : N;
    int gid = (blockIdx.x >> 3) * 256 + threadIdx.x;
    const int stride = (gridDim.x >> 3) * 256;
    for (; gid < E; gid += stride) {
        int d = dst[gid];
        if (d >= lo && d < hi) {
            int pos = atomicAdd(&cursor[d], 1);
            uint2 pk;
            pk.x = (u32)src[gid];
            pk.y = __builtin_bit_cast(u32, w[gid]);
            es_packed[pos] = pk;
        }
    }
}

__global__ void bn_prep(const float* __restrict__ b1, const float* __restrict__ gamma,
                        const float* __restrict__ beta, const float* __restrict__ mean,
                        const float* __restrict__ var, float* __restrict__ scale,
                        float* __restrict__ shift) {
    int f = threadIdx.x;
    if (f < HID) {
        float sc = gamma[f] * rsqrtf(var[f] + BN_EPS);
        scale[f] = sc;
        shift[f] = beta[f] + sc * (b1[f] - mean[f]);
    }
}

// ---------------------------------------------------------------------------
// Gather layer 1 (D=128 bf16): one wave per dst row, FOUR edges per
// iteration. Lane f = q*16+fc (q = edge-of-quad, fc = col-group); each lane
// loads uint4 = 8 bf16 cols of the q-th edge's source row. Partials merged
// with shfl_xor(16)+(32). Fused BN+ReLU epilogue; quarter 0 stores the row.
// ---------------------------------------------------------------------------
__global__ __launch_bounds__(256) void gather1_kernel(
        const u32* __restrict__ XWb, const int* __restrict__ row_ptr,
        const uint2* __restrict__ es, const float* __restrict__ scale,
        const float* __restrict__ shift, u32* __restrict__ Hb, int N) {
    int r = blockIdx.x * 4 + (threadIdx.x >> 6);
    if (r >= N) return;                     // wave-uniform
    int f = threadIdx.x & 63;
    int q = f >> 4;                         // edge within quad
    int fc = f & 15;                        // col group: bf16 cols 8fc..8fc+7
    int beg = row_ptr[r], end = row_ptr[r + 1];
    float acc[8];
    #pragma unroll
    for (int j = 0; j < 8; ++j) acc[j] = 0.f;
    for (int base = beg; base < end; base += 64) {
        int m = end - base; if (m > 64) m = 64;
        uint2 pk = (f < m) ? es[base + f] : make_uint2(0u, 0u);
        int   se = (int)pk.x;
        float we = __builtin_bit_cast(float, pk.y);
        for (int k = 0; k < m; k += 4) {
            int k0 = k + q;
            int   sk = __shfl(se, k0, 64);
            float wk = __shfl(we, k0, 64);
            uint4 x = *(const uint4*)&XWb[(size_t)sk * 64 + 4 * fc];
            acc[0] = fmaf(bf_lo(x.x), wk, acc[0]);
            acc[1] = fmaf(bf_hi(x.x), wk, acc[1]);
            acc[2] = fmaf(bf_lo(x.y), wk, acc[2]);
            acc[3] = fmaf(bf_hi(x.y), wk, acc[3]);
            acc[4] = fmaf(bf_lo(x.z), wk, acc[4]);
            acc[5] = fmaf(bf_hi(x.z), wk, acc[5]);
            acc[6] = fmaf(bf_lo(x.w), wk, acc[6]);
            acc[7] = fmaf(bf_hi(x.w), wk, acc[7]);
        }
    }
    #pragma unroll
    for (int j = 0; j < 8; ++j) {
        acc[j] += __shfl_xor(acc[j], 16, 64);
        acc[j] += __shfl_xor(acc[j], 32, 64);
    }
    if (q == 0) {
        float4 sc0 = *(const float4*)&scale[8 * fc];
        float4 sc1 = *(const float4*)&scale[8 * fc + 4];
        float4 sh0 = *(const float4*)&shift[8 * fc];
        float4 sh1 = *(const float4*)&shift[8 * fc + 4];
        float h0 = fmaf(acc[0], sc0.x, sh0.x);
        float h1 = fmaf(acc[1], sc0.y, sh0.y);
        float h2 = fmaf(acc[2], sc0.z, sh0.z);
        float h3 = fmaf(acc[3], sc0.w, sh0.w);
        float h4 = fmaf(acc[4], sc1.x, sh1.x);
        float h5 = fmaf(acc[5], sc1.y, sh1.y);
        float h6 = fmaf(acc[6], sc1.z, sh1.z);
        float h7 = fmaf(acc[7], sc1.w, sh1.w);
        uint4 o;
        o.x = pack2(h0 > 0.f ? h0 : 0.f, h1 > 0.f ? h1 : 0.f);
        o.y = pack2(h2 > 0.f ? h2 : 0.f, h3 > 0.f ? h3 : 0.f);
        o.z = pack2(h4 > 0.f ? h4 : 0.f, h5 > 0.f ? h5 : 0.f);
        o.w = pack2(h6 > 0.f ? h6 : 0.f, h7 > 0.f ? h7 : 0.f);
        *(uint4*)&Hb[(size_t)r * 64 + 4 * fc] = o;
    }
}

// ---------------------------------------------------------------------------
// Gather layer 2 (D=64 bf16) + epilogue: one wave per dst row, FOUR edges
// per iteration (16 lanes/edge, uint2 = 4 cols/lane). Quarter 0 writes.
// ---------------------------------------------------------------------------
__global__ __launch_bounds__(256) void gather2_final(
        const u32* __restrict__ XW2b, const int* __restrict__ row_ptr,
        const uint2* __restrict__ es, const float* __restrict__ b2,
        const float* __restrict__ prev, const int* __restrict__ sens,
        const int* __restrict__ ins, float* __restrict__ out_lsm,
        float* __restrict__ out_emb, int N) {
    int r = blockIdx.x * 4 + (threadIdx.x >> 6);
    if (r >= N) return;                     // wave-uniform
    int f = threadIdx.x & 63;
    int q = f >> 4;                         // edge within quad
    int fc = f & 15;                        // col group: bf16 cols 4fc..4fc+3
    int beg = row_ptr[r], end = row_ptr[r + 1];
    float a0 = 0.f, a1 = 0.f, a2 = 0.f, a3 = 0.f;
    for (int base = beg; base < end; base += 64) {
        int m = end - base; if (m > 64) m = 64;
        uint2 pk = (f < m) ? es[base + f] : make_uint2(0u, 0u);
        int   se = (int)pk.x;
        float we = __builtin_bit_cast(float, pk.y);
        for (int k = 0; k < m; k += 4) {
            int k0 = k + q;
            int   sk = __shfl(se, k0, 64);
            float wk = __shfl(we, k0, 64);
            uint2 x = *(const uint2*)&XW2b[(size_t)sk * 32 + 2 * fc];
            a0 = fmaf(bf_lo(x.x), wk, a0);
            a1 = fmaf(bf_hi(x.x), wk, a1);
            a2 = fmaf(bf_lo(x.y), wk, a2);
            a3 = fmaf(bf_hi(x.y), wk, a3);
        }
    }
    a0 += __shfl_xor(a0, 16, 64); a0 += __shfl_xor(a0, 32, 64);
    a1 += __shfl_xor(a1, 16, 64); a1 += __shfl_xor(a1, 32, 64);
    a2 += __shfl_xor(a2, 16, 64); a2 += __shfl_xor(a2, 32, 64);
    a3 += __shfl_xor(a3, 16, 64); a3 += __shfl_xor(a3, 32, 64);

    float4 bb = *(const float4*)&b2[4 * fc];
    float h0 = a0 + bb.x, h1 = a1 + bb.y, h2 = a2 + bb.z, h3 = a3 + bb.w;
    bool s_ = sens[r] != 0;
    bool i_ = ins[r] != 0;
    float4 pv = *(const float4*)&prev[(size_t)r * CDIM + 4 * fc];
    float o0 = (s_ ? h0 : pv.x) + (i_ ? h0 : 0.f);
    float o1 = (s_ ? h1 : pv.y) + (i_ ? h1 : 0.f);
    float o2 = (s_ ? h2 : pv.z) + (i_ ? h2 : 0.f);
    float o3 = (s_ ? h3 : pv.w) + (i_ ? h3 : 0.f);
    // log-softmax over 64 cols: local max/sum of 4, reduce over 16 lanes
    float mm = fmaxf(fmaxf(o0, o1), fmaxf(o2, o3));
    #pragma unroll
    for (int off = 8; off > 0; off >>= 1) mm = fmaxf(mm, __shfl_xor(mm, off, 64));
    float s = expf(o0 - mm) + expf(o1 - mm) + expf(o2 - mm) + expf(o3 - mm);
    #pragma unroll
    for (int off = 8; off > 0; off >>= 1) s += __shfl_xor(s, off, 64);
    float lse = mm + logf(s);
    if (q == 0) {
        *(float4*)&out_lsm[(size_t)r * CDIM + 4 * fc] =
            make_float4(o0 - lse, o1 - lse, o2 - lse, o3 - lse);
        *(float4*)&out_emb[(size_t)r * CDIM + 4 * fc] =
            make_float4(o0, o1, o2, o3);
    }
}

extern "C" void kernel_launch(void* const* d_in, const int* in_sizes, int n_in,
                              void* d_out, int out_size, void* d_ws, size_t ws_size,
                              hipStream_t stream) {
    const float* features = (const float*)d_in[0];
    const int*   esrc     = (const int*)d_in[1];
    const int*   edst     = (const int*)d_in[2];
    const float* ew       = (const float*)d_in[3];
    const float* W1       = (const float*)d_in[4];
    const float* b1       = (const float*)d_in[5];
    const float* gamma1   = (const float*)d_in[6];
    const float* beta1    = (const float*)d_in[7];
    const float* mean1    = (const float*)d_in[8];
    const float* var1     = (const float*)d_in[9];
    const float* W2       = (const float*)d_in[10];
    const float* b2       = (const float*)d_in[11];
    const float* prev     = (const float*)d_in[12];
    const int*   sens     = (const int*)d_in[13];
    const int*   ins      = (const int*)d_in[14];

    const int N = in_sizes[0] / F_IN;
    const int E = in_sizes[1];
    const int nb = (N + SCAN_CHUNK - 1) / SCAN_CHUNK;

    // ---- workspace layout (u32 words); es_packed kept 8B-aligned ----
    u32* xw1b  = (u32*)d_ws;                         // N*64  (128 bf16 cols)
    u32* hb    = xw1b + (size_t)N * 64;              // N*64
    u32* xw2b  = hb + (size_t)N * 64;                // N*32
    uint2* es_packed = (uint2*)(xw2b + (size_t)N * 32);  // E x 8B (aligned: 160N even)
    float* scale = (float*)(es_packed + E);          // 128
    float* shift = scale + HID;                      // 128
    int* row_ptr = (int*)(shift + HID);              // N+1
    int* cursor  = row_ptr + (N + 1);                // N (aliases counts)
    int* bsums   = cursor + N;                       // nb
    int* boffs   = bsums + nb;                       // nb

    float* out_lsm = (float*)d_out;
    float* out_emb = out_lsm + (size_t)N * CDIM;

    // ---- CSR build ----
    hipMemsetAsync(cursor, 0, (size_t)N * sizeof(int), stream);
    hist_kernel<<<(E + 255) / 256, 256, 0, stream>>>(edst, cursor, E);
    scan_sums<<<nb, 256, 0, stream>>>(cursor, bsums, N);
    scan_offsets<<<1, 64, 0, stream>>>(bsums, boffs, nb, row_ptr, N, E);
    scan_write<<<nb, 256, 0, stream>>>(cursor, boffs, row_ptr, cursor, N);
    // sliced fill: 2048 WGs = 8 slices x 256 WGs (8 WG/CU on one XCD each)
    fill_kernel<<<2048, 256, 0, stream>>>(esrc, edst, ew, cursor,
                                          es_packed, E, N);
    bn_prep<<<1, 128, 0, stream>>>(b1, gamma1, beta1, mean1, var1, scale, shift);

    // ---- layer 1 ----
    const int ntiles = (N + 127) / 128;
    gemm_xw1<<<ntiles, 256, 0, stream>>>(features, W1, xw1b, N);
    gather1_kernel<<<(N + 3) / 4, 256, 0, stream>>>(xw1b, row_ptr, es_packed,
                                                    scale, shift, hb, N);
    // ---- layer 2 ----
    gemm_xw2<<<ntiles, 256, 0, stream>>>(hb, W2, xw2b, N);
    gather2_final<<<(N + 3) / 4, 256, 0, stream>>>(xw2b, row_ptr, es_packed,
                                                   b2, prev, sens, ins,
                                                   out_lsm, out_emb, N);
}

// Round 4
// 529.097 us; speedup vs baseline: 1.0321x; 1.0092x over previous
//
#include <hip/hip_runtime.h>
#include <math.h>

#define F_IN 128
#define HID  128
#define CDIM 64
#define BN_EPS 1e-5f
#define SCAN_CHUNK 1024   // elements per scan block (256 thr x 4)

typedef unsigned int u32;
typedef unsigned short u16;

// bf16 helpers (RNE)
__device__ __forceinline__ float bf_lo(u32 p) {
    u32 x = p << 16; return __builtin_bit_cast(float, x);
}
__device__ __forceinline__ float bf_hi(u32 p) {
    u32 x = p & 0xffff0000u; return __builtin_bit_cast(float, x);
}
__device__ __forceinline__ u16 f2bf(float f) {
    u32 x = __builtin_bit_cast(u32, f);
    return (u16)((x + 0x7fffu + ((x >> 16) & 1u)) >> 16);
}
__device__ __forceinline__ u32 pack2(float a, float b) {
    return (u32)f2bf(a) | ((u32)f2bf(b) << 16);   // lo = even col
}

// ---------------------------------------------------------------------------
// GEMM1: Y[N,128](bf16) = X[N,128](fp32) @ W[128,128](fp32).
// ---------------------------------------------------------------------------
__global__ __launch_bounds__(256) void gemm_xw1(const float* __restrict__ X,
                                                const float* __restrict__ W,
                                                u32* __restrict__ Yb, int N) {
    __shared__ float Wl[64][128];    // 32 KB
    __shared__ float xs[128][64];    // 32 KB
    const int cg = (threadIdx.x & 15) * 8;
    const int rg = (threadIdx.x >> 4) * 8;
    const int ntiles = (N + 127) >> 7;
    for (int tile = blockIdx.x; tile < ntiles; tile += gridDim.x) {
        const int row0 = tile << 7;
        float acc[8][8];
        #pragma unroll
        for (int i = 0; i < 8; ++i)
            #pragma unroll
            for (int j = 0; j < 8; ++j) acc[i][j] = 0.f;

        for (int kc = 0; kc < 128; kc += 64) {
            __syncthreads();
            for (int i = threadIdx.x; i < 2048; i += 256) {
                int kr = i >> 5, c = (i & 31) * 4;
                *(float4*)&Wl[kr][c] = *(const float4*)&W[(size_t)(kc + kr) * HID + c];
            }
            for (int i = threadIdx.x; i < 2048; i += 256) {
                int r = i >> 4, c = (i & 15) * 4;
                int gr = row0 + r;
                float4 v = make_float4(0.f, 0.f, 0.f, 0.f);
                if (gr < N) v = *(const float4*)&X[(size_t)gr * F_IN + kc + c];
                *(float4*)&xs[r][c] = v;
            }
            __syncthreads();
            #pragma unroll 2
            for (int k = 0; k < 64; k += 2) {
                float2 a[8];
                #pragma unroll
                for (int i = 0; i < 8; ++i) a[i] = *(float2*)&xs[rg + i][k];
                float4 b00 = *(float4*)&Wl[k][cg];
                float4 b01 = *(float4*)&Wl[k][cg + 4];
                float4 b10 = *(float4*)&Wl[k + 1][cg];
                float4 b11 = *(float4*)&Wl[k + 1][cg + 4];
                #pragma unroll
                for (int i = 0; i < 8; ++i) {
                    acc[i][0] = fmaf(a[i].x, b00.x, acc[i][0]);
                    acc[i][1] = fmaf(a[i].x, b00.y, acc[i][1]);
                    acc[i][2] = fmaf(a[i].x, b00.z, acc[i][2]);
                    acc[i][3] = fmaf(a[i].x, b00.w, acc[i][3]);
                    acc[i][4] = fmaf(a[i].x, b01.x, acc[i][4]);
                    acc[i][5] = fmaf(a[i].x, b01.y, acc[i][5]);
                    acc[i][6] = fmaf(a[i].x, b01.z, acc[i][6]);
                    acc[i][7] = fmaf(a[i].x, b01.w, acc[i][7]);
                    acc[i][0] = fmaf(a[i].y, b10.x, acc[i][0]);
                    acc[i][1] = fmaf(a[i].y, b10.y, acc[i][1]);
                    acc[i][2] = fmaf(a[i].y, b10.z, acc[i][2]);
                    acc[i][3] = fmaf(a[i].y, b10.w, acc[i][3]);
                    acc[i][4] = fmaf(a[i].y, b11.x, acc[i][4]);
                    acc[i][5] = fmaf(a[i].y, b11.y, acc[i][5]);
                    acc[i][6] = fmaf(a[i].y, b11.z, acc[i][6]);
                    acc[i][7] = fmaf(a[i].y, b11.w, acc[i][7]);
                }
            }
        }
        #pragma unroll
        for (int i = 0; i < 8; ++i) {
            int gr = row0 + rg + i;
            if (gr < N) {
                uint4 o;
                o.x = pack2(acc[i][0], acc[i][1]);
                o.y = pack2(acc[i][2], acc[i][3]);
                o.z = pack2(acc[i][4], acc[i][5]);
                o.w = pack2(acc[i][6], acc[i][7]);
                *(uint4*)&Yb[(size_t)gr * 64 + (cg >> 1)] = o;
            }
        }
    }
}

// ---------------------------------------------------------------------------
// GEMM2: Y[N,64](bf16) = H[N,128](bf16) @ W[128,64](fp32).
// ---------------------------------------------------------------------------
__global__ __launch_bounds__(256) void gemm_xw2(const u32* __restrict__ Hb,
                                                const float* __restrict__ W,
                                                u32* __restrict__ Yb, int N) {
    __shared__ float Wl[64][64];     // 16 KB
    __shared__ float xs[128][64];    // 32 KB
    const int cg = (threadIdx.x & 15) * 4;
    const int rg = (threadIdx.x >> 4) * 8;
    const int ntiles = (N + 127) >> 7;
    for (int tile = blockIdx.x; tile < ntiles; tile += gridDim.x) {
        const int row0 = tile << 7;
        float acc[8][4];
        #pragma unroll
        for (int i = 0; i < 8; ++i)
            #pragma unroll
            for (int j = 0; j < 4; ++j) acc[i][j] = 0.f;

        for (int kc = 0; kc < 128; kc += 64) {
            __syncthreads();
            for (int i = threadIdx.x; i < 1024; i += 256) {          // W chunk
                int kr = i >> 4, c = (i & 15) * 4;
                *(float4*)&Wl[kr][c] = *(const float4*)&W[(size_t)(kc + kr) * CDIM + c];
            }
            for (int i = threadIdx.x; i < 2048; i += 256) {          // H chunk
                int r = i >> 4, uc = (i & 15) * 2;
                int gr = row0 + r;
                float4 v = make_float4(0.f, 0.f, 0.f, 0.f);
                if (gr < N) {
                    uint2 p = *(const uint2*)&Hb[(size_t)gr * 64 + (kc >> 1) + uc];
                    v = make_float4(bf_lo(p.x), bf_hi(p.x), bf_lo(p.y), bf_hi(p.y));
                }
                *(float4*)&xs[r][uc * 2] = v;
            }
            __syncthreads();
            #pragma unroll 2
            for (int k = 0; k < 64; k += 2) {
                float2 a[8];
                #pragma unroll
                for (int i = 0; i < 8; ++i) a[i] = *(float2*)&xs[rg + i][k];
                float4 b0 = *(float4*)&Wl[k][cg];
                float4 b1 = *(float4*)&Wl[k + 1][cg];
                #pragma unroll
                for (int i = 0; i < 8; ++i) {
                    acc[i][0] = fmaf(a[i].x, b0.x, acc[i][0]);
                    acc[i][1] = fmaf(a[i].x, b0.y, acc[i][1]);
                    acc[i][2] = fmaf(a[i].x, b0.z, acc[i][2]);
                    acc[i][3] = fmaf(a[i].x, b0.w, acc[i][3]);
                    acc[i][0] = fmaf(a[i].y, b1.x, acc[i][0]);
                    acc[i][1] = fmaf(a[i].y, b1.y, acc[i][1]);
                    acc[i][2] = fmaf(a[i].y, b1.z, acc[i][2]);
                    acc[i][3] = fmaf(a[i].y, b1.w, acc[i][3]);
                }
            }
        }
        #pragma unroll
        for (int i = 0; i < 8; ++i) {
            int gr = row0 + rg + i;
            if (gr < N) {
                uint2 o;
                o.x = pack2(acc[i][0], acc[i][1]);
                o.y = pack2(acc[i][2], acc[i][3]);
                *(uint2*)&Yb[(size_t)gr * 32 + (cg >> 1)] = o;
            }
        }
    }
}

// ---------------------------------------------------------------------------
// CSR build: histogram -> scan -> fill
// hist: nontemporal dst stream (don't evict the 400 KB counts array from L2).
// ---------------------------------------------------------------------------
__global__ __launch_bounds__(256) void hist_kernel(const int* __restrict__ dst,
                                                   int* __restrict__ counts, int E) {
    int gid = blockIdx.x * 256 + threadIdx.x;
    int stride = gridDim.x * 256;
    for (; gid < E; gid += stride)
        atomicAdd(&counts[__builtin_nontemporal_load(&dst[gid])], 1);
}

__global__ __launch_bounds__(256) void scan_sums(const int* __restrict__ counts,
                                                 int* __restrict__ bsums, int N) {
    __shared__ int sdata[256];
    int base = blockIdx.x * SCAN_CHUNK + threadIdx.x * 4;
    int t = 0;
    #pragma unroll
    for (int j = 0; j < 4; ++j) { int i = base + j; if (i < N) t += counts[i]; }
    sdata[threadIdx.x] = t; __syncthreads();
    for (int off = 128; off > 0; off >>= 1) {
        if (threadIdx.x < off) sdata[threadIdx.x] += sdata[threadIdx.x + off];
        __syncthreads();
    }
    if (threadIdx.x == 0) bsums[blockIdx.x] = sdata[0];
}

__global__ void scan_offsets(const int* __restrict__ bsums, int* __restrict__ boffs,
                             int nb, int* __restrict__ row_ptr, int N, int E) {
    if (threadIdx.x == 0 && blockIdx.x == 0) {
        int run = 0;
        for (int i = 0; i < nb; ++i) { boffs[i] = run; run += bsums[i]; }
        row_ptr[N] = E;
    }
}

__global__ __launch_bounds__(256) void scan_write(const int* __restrict__ counts,
                                                  const int* __restrict__ boffs,
                                                  int* __restrict__ row_ptr,
                                                  int* __restrict__ cursor, int N) {
    __shared__ int sdata[256];
    int base = blockIdx.x * SCAN_CHUNK + threadIdx.x * 4;
    int v[4]; int tsum = 0;
    #pragma unroll
    for (int j = 0; j < 4; ++j) {
        int i = base + j;
        v[j] = (i < N) ? counts[i] : 0;
        tsum += v[j];
    }
    sdata[threadIdx.x] = tsum; __syncthreads();
    for (int off = 1; off < 256; off <<= 1) {
        int t = (threadIdx.x >= off) ? sdata[threadIdx.x - off] : 0;
        __syncthreads();
        sdata[threadIdx.x] += t;
        __syncthreads();
    }
    int off0 = sdata[threadIdx.x] - tsum + boffs[blockIdx.x];
    #pragma unroll
    for (int j = 0; j < 4; ++j) {
        int i = base + j;
        if (i < N) { row_ptr[i] = off0; cursor[i] = off0; off0 += v[j]; }
    }
}

// ---------------------------------------------------------------------------
// fill: dst-sliced, XCD-aware (slice = blockIdx.x & 7 -> one XCD's L2 owns a
// contiguous ~1.6 MB es_packed window). NEW: the dst/src/w streams are
// NONTEMPORAL so they don't evict partially-filled es_packed lines from L2 —
// each 64B line accumulates all 8 stores in L2 and writes back once.
// ---------------------------------------------------------------------------
__global__ __launch_bounds__(256) void fill_kernel(const int* __restrict__ src,
                                                   const int* __restrict__ dst,
                                                   const float* __restrict__ w,
                                                   int* __restrict__ cursor,
                                                   uint2* __restrict__ es_packed,
                                                   int E, int N) {
    const int slice = blockIdx.x & 7;
    const int sw = (N + 7) >> 3;
    const int lo = slice * sw;
    const int hi = (lo + sw < N) ? (lo + sw) : N;
    int gid = (blockIdx.x >> 3) * 256 + threadIdx.x;
    const int stride = (gridDim.x >> 3) * 256;
    for (; gid < E; gid += stride) {
        int d = __builtin_nontemporal_load(&dst[gid]);
        if (d >= lo && d < hi) {
            int pos = atomicAdd(&cursor[d], 1);
            uint2 pk;
            pk.x = (u32)__builtin_nontemporal_load(&src[gid]);
            pk.y = __builtin_bit_cast(u32, __builtin_nontemporal_load(&w[gid]));
            es_packed[pos] = pk;
        }
    }
}

__global__ void bn_prep(const float* __restrict__ b1, const float* __restrict__ gamma,
                        const float* __restrict__ beta, const float* __restrict__ mean,
                        const float* __restrict__ var, float* __restrict__ scale,
                        float* __restrict__ shift) {
    int f = threadIdx.x;
    if (f < HID) {
        float sc = gamma[f] * rsqrtf(var[f] + BN_EPS);
        scale[f] = sc;
        shift[f] = beta[f] + sc * (b1[f] - mean[f]);
    }
}

// ---------------------------------------------------------------------------
// Gather layer 1 (D=128 bf16): one wave per dst row, FOUR edges per
// iteration. Lane f = q*16+fc (q = edge-of-quad, fc = col-group); each lane
// loads uint4 = 8 bf16 cols of the q-th edge's source row. Partials merged
// with shfl_xor(16)+(32). Fused BN+ReLU epilogue; quarter 0 stores the row.
// ---------------------------------------------------------------------------
__global__ __launch_bounds__(256) void gather1_kernel(
        const u32* __restrict__ XWb, const int* __restrict__ row_ptr,
        const uint2* __restrict__ es, const float* __restrict__ scale,
        const float* __restrict__ shift, u32* __restrict__ Hb, int N) {
    int r = blockIdx.x * 4 + (threadIdx.x >> 6);
    if (r >= N) return;                     // wave-uniform
    int f = threadIdx.x & 63;
    int q = f >> 4;                         // edge within quad
    int fc = f & 15;                        // col group: bf16 cols 8fc..8fc+7
    int beg = row_ptr[r], end = row_ptr[r + 1];
    float acc[8];
    #pragma unroll
    for (int j = 0; j < 8; ++j) acc[j] = 0.f;
    for (int base = beg; base < end; base += 64) {
        int m = end - base; if (m > 64) m = 64;
        uint2 pk = (f < m) ? es[base + f] : make_uint2(0u, 0u);
        int   se = (int)pk.x;
        float we = __builtin_bit_cast(float, pk.y);
        for (int k = 0; k < m; k += 4) {
            int k0 = k + q;
            int   sk = __shfl(se, k0, 64);
            float wk = __shfl(we, k0, 64);
            uint4 x = *(const uint4*)&XWb[(size_t)sk * 64 + 4 * fc];
            acc[0] = fmaf(bf_lo(x.x), wk, acc[0]);
            acc[1] = fmaf(bf_hi(x.x), wk, acc[1]);
            acc[2] = fmaf(bf_lo(x.y), wk, acc[2]);
            acc[3] = fmaf(bf_hi(x.y), wk, acc[3]);
            acc[4] = fmaf(bf_lo(x.z), wk, acc[4]);
            acc[5] = fmaf(bf_hi(x.z), wk, acc[5]);
            acc[6] = fmaf(bf_lo(x.w), wk, acc[6]);
            acc[7] = fmaf(bf_hi(x.w), wk, acc[7]);
        }
    }
    #pragma unroll
    for (int j = 0; j < 8; ++j) {
        acc[j] += __shfl_xor(acc[j], 16, 64);
        acc[j] += __shfl_xor(acc[j], 32, 64);
    }
    if (q == 0) {
        float4 sc0 = *(const float4*)&scale[8 * fc];
        float4 sc1 = *(const float4*)&scale[8 * fc + 4];
        float4 sh0 = *(const float4*)&shift[8 * fc];
        float4 sh1 = *(const float4*)&shift[8 * fc + 4];
        float h0 = fmaf(acc[0], sc0.x, sh0.x);
        float h1 = fmaf(acc[1], sc0.y, sh0.y);
        float h2 = fmaf(acc[2], sc0.z, sh0.z);
        float h3 = fmaf(acc[3], sc0.w, sh0.w);
        float h4 = fmaf(acc[4], sc1.x, sh1.x);
        float h5 = fmaf(acc[5], sc1.y, sh1.y);
        float h6 = fmaf(acc[6], sc1.z, sh1.z);
        float h7 = fmaf(acc[7], sc1.w, sh1.w);
        uint4 o;
        o.x = pack2(h0 > 0.f ? h0 : 0.f, h1 > 0.f ? h1 : 0.f);
        o.y = pack2(h2 > 0.f ? h2 : 0.f, h3 > 0.f ? h3 : 0.f);
        o.z = pack2(h4 > 0.f ? h4 : 0.f, h5 > 0.f ? h5 : 0.f);
        o.w = pack2(h6 > 0.f ? h6 : 0.f, h7 > 0.f ? h7 : 0.f);
        *(uint4*)&Hb[(size_t)r * 64 + 4 * fc] = o;
    }
}

// ---------------------------------------------------------------------------
// Gather layer 2 (D=64 bf16) + epilogue: one wave per dst row, FOUR edges
// per iteration (16 lanes/edge, uint2 = 4 cols/lane). Quarter 0 writes.
// ---------------------------------------------------------------------------
__global__ __launch_bounds__(256) void gather2_final(
        const u32* __restrict__ XW2b, const int* __restrict__ row_ptr,
        const uint2* __restrict__ es, const float* __restrict__ b2,
        const float* __restrict__ prev, const int* __restrict__ sens,
        const int* __restrict__ ins, float* __restrict__ out_lsm,
        float* __restrict__ out_emb, int N) {
    int r = blockIdx.x * 4 + (threadIdx.x >> 6);
    if (r >= N) return;                     // wave-uniform
    int f = threadIdx.x & 63;
    int q = f >> 4;                         // edge within quad
    int fc = f & 15;                        // col group: bf16 cols 4fc..4fc+3
    int beg = row_ptr[r], end = row_ptr[r + 1];
    float a0 = 0.f, a1 = 0.f, a2 = 0.f, a3 = 0.f;
    for (int base = beg; base < end; base += 64) {
        int m = end - base; if (m > 64) m = 64;
        uint2 pk = (f < m) ? es[base + f] : make_uint2(0u, 0u);
        int   se = (int)pk.x;
        float we = __builtin_bit_cast(float, pk.y);
        for (int k = 0; k < m; k += 4) {
            int k0 = k + q;
            int   sk = __shfl(se, k0, 64);
            float wk = __shfl(we, k0, 64);
            uint2 x = *(const uint2*)&XW2b[(size_t)sk * 32 + 2 * fc];
            a0 = fmaf(bf_lo(x.x), wk, a0);
            a1 = fmaf(bf_hi(x.x), wk, a1);
            a2 = fmaf(bf_lo(x.y), wk, a2);
            a3 = fmaf(bf_hi(x.y), wk, a3);
        }
    }
    a0 += __shfl_xor(a0, 16, 64); a0 += __shfl_xor(a0, 32, 64);
    a1 += __shfl_xor(a1, 16, 64); a1 += __shfl_xor(a1, 32, 64);
    a2 += __shfl_xor(a2, 16, 64); a2 += __shfl_xor(a2, 32, 64);
    a3 += __shfl_xor(a3, 16, 64); a3 += __shfl_xor(a3, 32, 64);

    float4 bb = *(const float4*)&b2[4 * fc];
    float h0 = a0 + bb.x, h1 = a1 + bb.y, h2 = a2 + bb.z, h3 = a3 + bb.w;
    bool s_ = sens[r] != 0;
    bool i_ = ins[r] != 0;
    float4 pv = *(const float4*)&prev[(size_t)r * CDIM + 4 * fc];
    float o0 = (s_ ? h0 : pv.x) + (i_ ? h0 : 0.f);
    float o1 = (s_ ? h1 : pv.y) + (i_ ? h1 : 0.f);
    float o2 = (s_ ? h2 : pv.z) + (i_ ? h2 : 0.f);
    float o3 = (s_ ? h3 : pv.w) + (i_ ? h3 : 0.f);
    // log-softmax over 64 cols: local max/sum of 4, reduce over 16 lanes
    float mm = fmaxf(fmaxf(o0, o1), fmaxf(o2, o3));
    #pragma unroll
    for (int off = 8; off > 0; off >>= 1) mm = fmaxf(mm, __shfl_xor(mm, off, 64));
    float s = expf(o0 - mm) + expf(o1 - mm) + expf(o2 - mm) + expf(o3 - mm);
    #pragma unroll
    for (int off = 8; off > 0; off >>= 1) s += __shfl_xor(s, off, 64);
    float lse = mm + logf(s);
    if (q == 0) {
        *(float4*)&out_lsm[(size_t)r * CDIM + 4 * fc] =
            make_float4(o0 - lse, o1 - lse, o2 - lse, o3 - lse);
        *(float4*)&out_emb[(size_t)r * CDIM + 4 * fc] =
            make_float4(o0, o1, o2, o3);
    }
}

extern "C" void kernel_launch(void* const* d_in, const int* in_sizes, int n_in,
                              void* d_out, int out_size, void* d_ws, size_t ws_size,
                              hipStream_t stream) {
    const float* features = (const float*)d_in[0];
    const int*   esrc     = (const int*)d_in[1];
    const int*   edst     = (const int*)d_in[2];
    const float* ew       = (const float*)d_in[3];
    const float* W1       = (const float*)d_in[4];
    const float* b1       = (const float*)d_in[5];
    const float* gamma1   = (const float*)d_in[6];
    const float* beta1    = (const float*)d_in[7];
    const float* mean1    = (const float*)d_in[8];
    const float* var1     = (const float*)d_in[9];
    const float* W2       = (const float*)d_in[10];
    const float* b2       = (const float*)d_in[11];
    const float* prev     = (const float*)d_in[12];
    const int*   sens     = (const int*)d_in[13];
    const int*   ins      = (const int*)d_in[14];

    const int N = in_sizes[0] / F_IN;
    const int E = in_sizes[1];
    const int nb = (N + SCAN_CHUNK - 1) / SCAN_CHUNK;

    // ---- workspace layout (u32 words); es_packed kept 8B-aligned ----
    u32* xw1b  = (u32*)d_ws;                         // N*64  (128 bf16 cols)
    u32* hb    = xw1b + (size_t)N * 64;              // N*64
    u32* xw2b  = hb + (size_t)N * 64;                // N*32
    uint2* es_packed = (uint2*)(xw2b + (size_t)N * 32);  // E x 8B (aligned: 160N even)
    float* scale = (float*)(es_packed + E);          // 128
    float* shift = scale + HID;                      // 128
    int* row_ptr = (int*)(shift + HID);              // N+1
    int* cursor  = row_ptr + (N + 1);                // N (aliases counts)
    int* bsums   = cursor + N;                       // nb
    int* boffs   = bsums + nb;                       // nb

    float* out_lsm = (float*)d_out;
    float* out_emb = out_lsm + (size_t)N * CDIM;

    // ---- CSR build ----
    hipMemsetAsync(cursor, 0, (size_t)N * sizeof(int), stream);
    hist_kernel<<<(E + 255) / 256, 256, 0, stream>>>(edst, cursor, E);
    scan_sums<<<nb, 256, 0, stream>>>(cursor, bsums, N);
    scan_offsets<<<1, 64, 0, stream>>>(bsums, boffs, nb, row_ptr, N, E);
    scan_write<<<nb, 256, 0, stream>>>(cursor, boffs, row_ptr, cursor, N);
    // sliced fill: 2048 WGs = 8 slices x 256 WGs (8 WG/CU on one XCD each)
    fill_kernel<<<2048, 256, 0, stream>>>(esrc, edst, ew, cursor,
                                          es_packed, E, N);
    bn_prep<<<1, 128, 0, stream>>>(b1, gamma1, beta1, mean1, var1, scale, shift);

    // ---- layer 1 ----
    const int ntiles = (N + 127) / 128;
    gemm_xw1<<<ntiles, 256, 0, stream>>>(features, W1, xw1b, N);
    gather1_kernel<<<(N + 3) / 4, 256, 0, stream>>>(xw1b, row_ptr, es_packed,
                                                    scale, shift, hb, N);
    // ---- layer 2 ----
    gemm_xw2<<<ntiles, 256, 0, stream>>>(hb, W2, xw2b, N);
    gather2_final<<<(N + 3) / 4, 256, 0, stream>>>(xw2b, row_ptr, es_packed,
                                                   b2, prev, sens, ins,
                                                   out_lsm, out_emb, N);
}

// Round 10
// 463.458 us; speedup vs baseline: 1.1783x; 1.1416x over previous
//
#include <hip/hip_runtime.h>
#include <math.h>

#define F_IN 128
#define HID  128
#define CDIM 64
#define BN_EPS 1e-5f
#define SCAN_CHUNK 1024   // elements per scan block (256 thr x 4)

typedef unsigned int u32;
typedef unsigned short u16;
typedef __attribute__((ext_vector_type(8))) short bf16x8;   // 8 bf16 = 4 VGPR
typedef __attribute__((ext_vector_type(4))) float f32x4;

// bf16 helpers (RNE)
__device__ __forceinline__ float bf_lo(u32 p) {
    u32 x = p << 16; return __builtin_bit_cast(float, x);
}
__device__ __forceinline__ float bf_hi(u32 p) {
    u32 x = p & 0xffff0000u; return __builtin_bit_cast(float, x);
}
__device__ __forceinline__ u16 f2bf(float f) {
    u32 x = __builtin_bit_cast(u32, f);
    return (u16)((x + 0x7fffu + ((x >> 16) & 1u)) >> 16);
}
__device__ __forceinline__ u32 pack2(float a, float b) {
    return (u32)f2bf(a) | ((u32)f2bf(b) << 16);   // lo = even col
}

// Swizzled LDS fragment load: element k of row r lives at u16 index
// r*128 + (k ^ ((r&7)<<3)). XOR touches bits 3-5 only, so 8-aligned k
// stays 8-aligned -> 16B ds_read_b128. Breaks the 32-way row-stride-256B
// bank conflict (G4 recipe).
__device__ __forceinline__ bf16x8 frag_ld(const u16* lds, int row, int kb) {
    return *(const bf16x8*)&lds[row * 128 + (kb ^ ((row & 7) << 3))];
}

// ---------------------------------------------------------------------------
// wt_prep: build pre-transposed, pre-swizzled bf16 weight images in workspace.
// wt1[c][k] = bf16(W1[k][c]) at u16 idx c*128 + (k ^ ((c&7)<<3))   (32 KB)
// wt2[c][k] = bf16(W2[k][c]) at u16 idx c*128 + (k ^ ((c&7)<<3))   (16 KB)
// ---------------------------------------------------------------------------
__global__ __launch_bounds__(256) void wt_prep(const float* __restrict__ W1,
                                               const float* __restrict__ W2,
                                               u16* __restrict__ wt1,
                                               u16* __restrict__ wt2) {
    int t = blockIdx.x * 256 + threadIdx.x;
    if (t < 128 * 128) {
        int k = t >> 7, c = t & 127;
        wt1[c * 128 + (k ^ ((c & 7) << 3))] = f2bf(W1[t]);   // W1[k*128+c]
    } else if (t < 128 * 128 + 128 * 64) {
        int t2 = t - 128 * 128;
        int k = t2 >> 6, c = t2 & 63;
        wt2[c * 128 + (k ^ ((c & 7) << 3))] = f2bf(W2[t2]);  // W2[k*64+c]
    }
}

// ---------------------------------------------------------------------------
// GEMM1 (MFMA): Y[N,128](bf16) = X[N,128](fp32->bf16) @ W1.
// Transposed formulation D' = Wt * X^T per 16x16 tile:
//   A-frag lane l elem j : Wt[ct*16 + (l&15)][k0 + (l>>4)*8 + j]
//   B-frag lane l elem j : X [r0  + (l&15)][k0 + (l>>4)*8 + j]
//   D'    lane l reg  r  : Y [r0 + (l&15)][ct*16 + (l>>4)*4 + r]
// -> each lane packs 4 consecutive output cols of one row into a uint2.
// Block = 256 thr (4 waves), tile = 64 rows x 128 cols, LDS 48 KB (3 blk/CU).
// ---------------------------------------------------------------------------
__global__ __launch_bounds__(256) void gemm_xw1_mfma(const float* __restrict__ X,
                                                     const u16* __restrict__ wt1,
                                                     u32* __restrict__ Yb, int N) {
    __shared__ u16 wl[128 * 128];   // 32 KB (swizzled Wt)
    __shared__ u16 xl[64 * 128];    // 16 KB (swizzled X tile, bf16)
    // stage W once per block (linear copy; image is pre-swizzled)
    for (int i = threadIdx.x; i < 2048; i += 256)
        ((uint4*)wl)[i] = ((const uint4*)wt1)[i];
    const int l  = threadIdx.x & 63;
    const int wv = threadIdx.x >> 6;
    const int r16 = wv * 16;
    const int lr = l & 15;
    const int kq = l >> 4;
    const int ntiles = (N + 63) >> 6;
    for (int tile = blockIdx.x; tile < ntiles; tile += gridDim.x) {
        const int row0 = tile << 6;
        __syncthreads();   // previous iteration's reads done before restage
        // stage X tile 64x128 fp32 -> bf16, swizzled
        for (int i = threadIdx.x; i < 2048; i += 256) {
            int r = i >> 5, c4 = i & 31;       // c4: float4 index (k = c4*4)
            int gr = row0 + r;
            float4 v = make_float4(0.f, 0.f, 0.f, 0.f);
            if (gr < N) v = *(const float4*)&X[(size_t)gr * F_IN + c4 * 4];
            uint2 p;
            p.x = pack2(v.x, v.y);
            p.y = pack2(v.z, v.w);
            *(uint2*)&xl[r * 128 + ((c4 * 4) ^ ((r & 7) << 3))] = p;
        }
        __syncthreads();
        f32x4 acc[8];
        #pragma unroll
        for (int c = 0; c < 8; ++c) acc[c] = (f32x4){0.f, 0.f, 0.f, 0.f};
        #pragma unroll
        for (int k0 = 0; k0 < 128; k0 += 32) {
            int kb = k0 + kq * 8;
            bf16x8 xf = frag_ld(xl, r16 + lr, kb);
            #pragma unroll
            for (int c = 0; c < 8; ++c) {
                bf16x8 wf = frag_ld(wl, c * 16 + lr, kb);
                acc[c] = __builtin_amdgcn_mfma_f32_16x16x32_bf16(wf, xf, acc[c], 0, 0, 0);
            }
        }
        int grow = row0 + r16 + lr;
        if (grow < N) {
            #pragma unroll
            for (int c = 0; c < 8; ++c) {
                uint2 o;
                o.x = pack2(acc[c][0], acc[c][1]);
                o.y = pack2(acc[c][2], acc[c][3]);
                *(uint2*)&Yb[(size_t)grow * 64 + c * 8 + kq * 2] = o;
            }
        }
    }
}

// ---------------------------------------------------------------------------
// GEMM2 (MFMA): Y[N,64](bf16) = H[N,128](bf16) @ W2. Same structure,
// 4 col-tiles, LDS 32 KB (5 blk/CU). H already bf16 -> uint4 copy staging.
// ---------------------------------------------------------------------------
__global__ __launch_bounds__(256) void gemm_xw2_mfma(const u32* __restrict__ Hb,
                                                     const u16* __restrict__ wt2,
                                                     u32* __restrict__ Yb, int N) {
    __shared__ u16 wl[64 * 128];    // 16 KB
    __shared__ u16 xl[64 * 128];    // 16 KB
    for (int i = threadIdx.x; i < 1024; i += 256)
        ((uint4*)wl)[i] = ((const uint4*)wt2)[i];
    const int l  = threadIdx.x & 63;
    const int wv = threadIdx.x >> 6;
    const int r16 = wv * 16;
    const int lr = l & 15;
    const int kq = l >> 4;
    const int ntiles = (N + 63) >> 6;
    for (int tile = blockIdx.x; tile < ntiles; tile += gridDim.x) {
        const int row0 = tile << 6;
        __syncthreads();
        // stage H tile 64 rows x 128 bf16 cols, swizzled (uint4 = 8 bf16)
        for (int i = threadIdx.x; i < 1024; i += 256) {
            int r = i >> 4, c8 = i & 15;       // k = c8*8
            int gr = row0 + r;
            uint4 v = make_uint4(0u, 0u, 0u, 0u);
            if (gr < N) v = *(const uint4*)&Hb[(size_t)gr * 64 + c8 * 4];
            *(uint4*)&xl[r * 128 + ((c8 * 8) ^ ((r & 7) << 3))] = v;
        }
        __syncthreads();
        f32x4 acc[4];
        #pragma unroll
        for (int c = 0; c < 4; ++c) acc[c] = (f32x4){0.f, 0.f, 0.f, 0.f};
        #pragma unroll
        for (int k0 = 0; k0 < 128; k0 += 32) {
            int kb = k0 + kq * 8;
            bf16x8 xf = frag_ld(xl, r16 + lr, kb);
            #pragma unroll
            for (int c = 0; c < 4; ++c) {
                bf16x8 wf = frag_ld(wl, c * 16 + lr, kb);
                acc[c] = __builtin_amdgcn_mfma_f32_16x16x32_bf16(wf, xf, acc[c], 0, 0, 0);
            }
        }
        int grow = row0 + r16 + lr;
        if (grow < N) {
            #pragma unroll
            for (int c = 0; c < 4; ++c) {
                uint2 o;
                o.x = pack2(acc[c][0], acc[c][1]);
                o.y = pack2(acc[c][2], acc[c][3]);
                *(uint2*)&Yb[(size_t)grow * 32 + c * 8 + kq * 2] = o;
            }
        }
    }
}

// ---------------------------------------------------------------------------
// CSR build: histogram -> scan -> fill
// ---------------------------------------------------------------------------
__global__ __launch_bounds__(256) void hist_kernel(const int* __restrict__ dst,
                                                   int* __restrict__ counts, int E) {
    int gid = blockIdx.x * 256 + threadIdx.x;
    int stride = gridDim.x * 256;
    for (; gid < E; gid += stride)
        atomicAdd(&counts[__builtin_nontemporal_load(&dst[gid])], 1);
}

__global__ __launch_bounds__(256) void scan_sums(const int* __restrict__ counts,
                                                 int* __restrict__ bsums, int N) {
    __shared__ int sdata[256];
    int base = blockIdx.x * SCAN_CHUNK + threadIdx.x * 4;
    int t = 0;
    #pragma unroll
    for (int j = 0; j < 4; ++j) { int i = base + j; if (i < N) t += counts[i]; }
    sdata[threadIdx.x] = t; __syncthreads();
    for (int off = 128; off > 0; off >>= 1) {
        if (threadIdx.x < off) sdata[threadIdx.x] += sdata[threadIdx.x + off];
        __syncthreads();
    }
    if (threadIdx.x == 0) bsums[blockIdx.x] = sdata[0];
}

__global__ void scan_offsets(const int* __restrict__ bsums, int* __restrict__ boffs,
                             int nb, int* __restrict__ row_ptr, int N, int E) {
    if (threadIdx.x == 0 && blockIdx.x == 0) {
        int run = 0;
        for (int i = 0; i < nb; ++i) { boffs[i] = run; run += bsums[i]; }
        row_ptr[N] = E;
    }
}

__global__ __launch_bounds__(256) void scan_write(const int* __restrict__ counts,
                                                  const int* __restrict__ boffs,
                                                  int* __restrict__ row_ptr,
                                                  int* __restrict__ cursor, int N) {
    __shared__ int sdata[256];
    int base = blockIdx.x * SCAN_CHUNK + threadIdx.x * 4;
    int v[4]; int tsum = 0;
    #pragma unroll
    for (int j = 0; j < 4; ++j) {
        int i = base + j;
        v[j] = (i < N) ? counts[i] : 0;
        tsum += v[j];
    }
    sdata[threadIdx.x] = tsum; __syncthreads();
    for (int off = 1; off < 256; off <<= 1) {
        int t = (threadIdx.x >= off) ? sdata[threadIdx.x - off] : 0;
        __syncthreads();
        sdata[threadIdx.x] += t;
        __syncthreads();
    }
    int off0 = sdata[threadIdx.x] - tsum + boffs[blockIdx.x];
    #pragma unroll
    for (int j = 0; j < 4; ++j) {
        int i = base + j;
        if (i < N) { row_ptr[i] = off0; cursor[i] = off0; off0 += v[j]; }
    }
}

// ---------------------------------------------------------------------------
// fill: dst-sliced, XCD-aware; nontemporal edge streams.
// ---------------------------------------------------------------------------
__global__ __launch_bounds__(256) void fill_kernel(const int* __restrict__ src,
                                                   const int* __restrict__ dst,
                                                   const float* __restrict__ w,
                                                   int* __restrict__ cursor,
                                                   uint2* __restrict__ es_packed,
                                                   int E, int N) {
    const int slice = blockIdx.x & 7;
    const int sw = (N + 7) >> 3;
    const int lo = slice * sw;
    const int hi = (lo + sw < N) ? (lo + sw) : N;
    int gid = (blockIdx.x >> 3) * 256 + threadIdx.x;
    const int stride = (gridDim.x >> 3) * 256;
    for (; gid < E; gid += stride) {
        int d = __builtin_nontemporal_load(&dst[gid]);
        if (d >= lo && d < hi) {
            int pos = atomicAdd(&cursor[d], 1);
            uint2 pk;
            pk.x = (u32)__builtin_nontemporal_load(&src[gid]);
            pk.y = __builtin_bit_cast(u32, __builtin_nontemporal_load(&w[gid]));
            es_packed[pos] = pk;
        }
    }
}

__global__ void bn_prep(const float* __restrict__ b1, const float* __restrict__ gamma,
                        const float* __restrict__ beta, const float* __restrict__ mean,
                        const float* __restrict__ var, float* __restrict__ scale,
                        float* __restrict__ shift) {
    int f = threadIdx.x;
    if (f < HID) {
        float sc = gamma[f] * rsqrtf(var[f] + BN_EPS);
        scale[f] = sc;
        shift[f] = beta[f] + sc * (b1[f] - mean[f]);
    }
}

// ---------------------------------------------------------------------------
// Gather layer 1 (D=128 bf16): one wave per dst row, four edges/iteration.
// ---------------------------------------------------------------------------
__global__ __launch_bounds__(256) void gather1_kernel(
        const u32* __restrict__ XWb, const int* __restrict__ row_ptr,
        const uint2* __restrict__ es, const float* __restrict__ scale,
        const float* __restrict__ shift, u32* __restrict__ Hb, int N) {
    int r = blockIdx.x * 4 + (threadIdx.x >> 6);
    if (r >= N) return;                     // wave-uniform
    int f = threadIdx.x & 63;
    int q = f >> 4;                         // edge within quad
    int fc = f & 15;                        // col group: bf16 cols 8fc..8fc+7
    int beg = row_ptr[r], end = row_ptr[r + 1];
    float acc[8];
    #pragma unroll
    for (int j = 0; j < 8; ++j) acc[j] = 0.f;
    for (int base = beg; base < end; base += 64) {
        int m = end - base; if (m > 64) m = 64;
        uint2 pk = (f < m) ? es[base + f] : make_uint2(0u, 0u);
        int   se = (int)pk.x;
        float we = __builtin_bit_cast(float, pk.y);
        for (int k = 0; k < m; k += 4) {
            int k0 = k + q;
            int   sk = __shfl(se, k0, 64);
            float wk = __shfl(we, k0, 64);
            uint4 x = *(const uint4*)&XWb[(size_t)sk * 64 + 4 * fc];
            acc[0] = fmaf(bf_lo(x.x), wk, acc[0]);
            acc[1] = fmaf(bf_hi(x.x), wk, acc[1]);
            acc[2] = fmaf(bf_lo(x.y), wk, acc[2]);
            acc[3] = fmaf(bf_hi(x.y), wk, acc[3]);
            acc[4] = fmaf(bf_lo(x.z), wk, acc[4]);
            acc[5] = fmaf(bf_hi(x.z), wk, acc[5]);
            acc[6] = fmaf(bf_lo(x.w), wk, acc[6]);
            acc[7] = fmaf(bf_hi(x.w), wk, acc[7]);
        }
    }
    #pragma unroll
    for (int j = 0; j < 8; ++j) {
        acc[j] += __shfl_xor(acc[j], 16, 64);
        acc[j] += __shfl_xor(acc[j], 32, 64);
    }
    if (q == 0) {
        float4 sc0 = *(const float4*)&scale[8 * fc];
        float4 sc1 = *(const float4*)&scale[8 * fc + 4];
        float4 sh0 = *(const float4*)&shift[8 * fc];
        float4 sh1 = *(const float4*)&shift[8 * fc + 4];
        float h0 = fmaf(acc[0], sc0.x, sh0.x);
        float h1 = fmaf(acc[1], sc0.y, sh0.y);
        float h2 = fmaf(acc[2], sc0.z, sh0.z);
        float h3 = fmaf(acc[3], sc0.w, sh0.w);
        float h4 = fmaf(acc[4], sc1.x, sh1.x);
        float h5 = fmaf(acc[5], sc1.y, sh1.y);
        float h6 = fmaf(acc[6], sc1.z, sh1.z);
        float h7 = fmaf(acc[7], sc1.w, sh1.w);
        uint4 o;
        o.x = pack2(h0 > 0.f ? h0 : 0.f, h1 > 0.f ? h1 : 0.f);
        o.y = pack2(h2 > 0.f ? h2 : 0.f, h3 > 0.f ? h3 : 0.f);
        o.z = pack2(h4 > 0.f ? h4 : 0.f, h5 > 0.f ? h5 : 0.f);
        o.w = pack2(h6 > 0.f ? h6 : 0.f, h7 > 0.f ? h7 : 0.f);
        *(uint4*)&Hb[(size_t)r * 64 + 4 * fc] = o;
    }
}

// ---------------------------------------------------------------------------
// Gather layer 2 (D=64 bf16) + epilogue.
// ---------------------------------------------------------------------------
__global__ __launch_bounds__(256) void gather2_final(
        const u32* __restrict__ XW2b, const int* __restrict__ row_ptr,
        const uint2* __restrict__ es, const float* __restrict__ b2,
        const float* __restrict__ prev, const int* __restrict__ sens,
        const int* __restrict__ ins, float* __restrict__ out_lsm,
        float* __restrict__ out_emb, int N) {
    int r = blockIdx.x * 4 + (threadIdx.x >> 6);
    if (r >= N) return;                     // wave-uniform
    int f = threadIdx.x & 63;
    int q = f >> 4;                         // edge within quad
    int fc = f & 15;                        // col group: bf16 cols 4fc..4fc+3
    int beg = row_ptr[r], end = row_ptr[r + 1];
    float a0 = 0.f, a1 = 0.f, a2 = 0.f, a3 = 0.f;
    for (int base = beg; base < end; base += 64) {
        int m = end - base; if (m > 64) m = 64;
        uint2 pk = (f < m) ? es[base + f] : make_uint2(0u, 0u);
        int   se = (int)pk.x;
        float we = __builtin_bit_cast(float, pk.y);
        for (int k = 0; k < m; k += 4) {
            int k0 = k + q;
            int   sk = __shfl(se, k0, 64);
            float wk = __shfl(we, k0, 64);
            uint2 x = *(const uint2*)&XW2b[(size_t)sk * 32 + 2 * fc];
            a0 = fmaf(bf_lo(x.x), wk, a0);
            a1 = fmaf(bf_hi(x.x), wk, a1);
            a2 = fmaf(bf_lo(x.y), wk, a2);
            a3 = fmaf(bf_hi(x.y), wk, a3);
        }
    }
    a0 += __shfl_xor(a0, 16, 64); a0 += __shfl_xor(a0, 32, 64);
    a1 += __shfl_xor(a1, 16, 64); a1 += __shfl_xor(a1, 32, 64);
    a2 += __shfl_xor(a2, 16, 64); a2 += __shfl_xor(a2, 32, 64);
    a3 += __shfl_xor(a3, 16, 64); a3 += __shfl_xor(a3, 32, 64);

    float4 bb = *(const float4*)&b2[4 * fc];
    float h0 = a0 + bb.x, h1 = a1 + bb.y, h2 = a2 + bb.z, h3 = a3 + bb.w;
    bool s_ = sens[r] != 0;
    bool i_ = ins[r] != 0;
    float4 pv = *(const float4*)&prev[(size_t)r * CDIM + 4 * fc];
    float o0 = (s_ ? h0 : pv.x) + (i_ ? h0 : 0.f);
    float o1 = (s_ ? h1 : pv.y) + (i_ ? h1 : 0.f);
    float o2 = (s_ ? h2 : pv.z) + (i_ ? h2 : 0.f);
    float o3 = (s_ ? h3 : pv.w) + (i_ ? h3 : 0.f);
    // log-softmax over 64 cols: local max/sum of 4, reduce over 16 lanes
    float mm = fmaxf(fmaxf(o0, o1), fmaxf(o2, o3));
    #pragma unroll
    for (int off = 8; off > 0; off >>= 1) mm = fmaxf(mm, __shfl_xor(mm, off, 64));
    float s = expf(o0 - mm) + expf(o1 - mm) + expf(o2 - mm) + expf(o3 - mm);
    #pragma unroll
    for (int off = 8; off > 0; off >>= 1) s += __shfl_xor(s, off, 64);
    float lse = mm + logf(s);
    if (q == 0) {
        *(float4*)&out_lsm[(size_t)r * CDIM + 4 * fc] =
            make_float4(o0 - lse, o1 - lse, o2 - lse, o3 - lse);
        *(float4*)&out_emb[(size_t)r * CDIM + 4 * fc] =
            make_float4(o0, o1, o2, o3);
    }
}

extern "C" void kernel_launch(void* const* d_in, const int* in_sizes, int n_in,
                              void* d_out, int out_size, void* d_ws, size_t ws_size,
                              hipStream_t stream) {
    const float* features = (const float*)d_in[0];
    const int*   esrc     = (const int*)d_in[1];
    const int*   edst     = (const int*)d_in[2];
    const float* ew       = (const float*)d_in[3];
    const float* W1       = (const float*)d_in[4];
    const float* b1       = (const float*)d_in[5];
    const float* gamma1   = (const float*)d_in[6];
    const float* beta1    = (const float*)d_in[7];
    const float* mean1    = (const float*)d_in[8];
    const float* var1     = (const float*)d_in[9];
    const float* W2       = (const float*)d_in[10];
    const float* b2       = (const float*)d_in[11];
    const float* prev     = (const float*)d_in[12];
    const int*   sens     = (const int*)d_in[13];
    const int*   ins      = (const int*)d_in[14];

    const int N = in_sizes[0] / F_IN;
    const int E = in_sizes[1];
    const int nb = (N + SCAN_CHUNK - 1) / SCAN_CHUNK;

    // ---- workspace layout (u32 words) ----
    u16* wt1   = (u16*)d_ws;                         // 128*128 u16 = 8192 u32
    u16* wt2   = wt1 + 128 * 128;                    // 64*128 u16  = 4096 u32
    u32* xw1b  = (u32*)d_ws + 12288;                 // N*64  (128 bf16 cols)
    u32* hb    = xw1b + (size_t)N * 64;              // N*64
    u32* xw2b  = hb + (size_t)N * 64;                // N*32
    uint2* es_packed = (uint2*)(xw2b + (size_t)N * 32);  // E x 8B (8B-aligned)
    float* scale = (float*)(es_packed + E);          // 128
    float* shift = scale + HID;                      // 128
    int* row_ptr = (int*)(shift + HID);              // N+1
    int* cursor  = row_ptr + (N + 1);                // N (aliases counts)
    int* bsums   = cursor + N;                       // nb
    int* boffs   = bsums + nb;                       // nb

    float* out_lsm = (float*)d_out;
    float* out_emb = out_lsm + (size_t)N * CDIM;

    // ---- weight prep (bf16, transposed, swizzled) ----
    wt_prep<<<96, 256, 0, stream>>>(W1, W2, wt1, wt2);

    // ---- CSR build ----
    hipMemsetAsync(cursor, 0, (size_t)N * sizeof(int), stream);
    hist_kernel<<<(E + 255) / 256, 256, 0, stream>>>(edst, cursor, E);
    scan_sums<<<nb, 256, 0, stream>>>(cursor, bsums, N);
    scan_offsets<<<1, 64, 0, stream>>>(bsums, boffs, nb, row_ptr, N, E);
    scan_write<<<nb, 256, 0, stream>>>(cursor, boffs, row_ptr, cursor, N);
    // sliced fill: 2048 WGs = 8 slices x 256 WGs
    fill_kernel<<<2048, 256, 0, stream>>>(esrc, edst, ew, cursor,
                                          es_packed, E, N);
    bn_prep<<<1, 128, 0, stream>>>(b1, gamma1, beta1, mean1, var1, scale, shift);

    // ---- layer 1 ----
    const int nt64 = (N + 63) / 64;
    gemm_xw1_mfma<<<nt64, 256, 0, stream>>>(features, wt1, xw1b, N);
    gather1_kernel<<<(N + 3) / 4, 256, 0, stream>>>(xw1b, row_ptr, es_packed,
                                                    scale, shift, hb, N);
    // ---- layer 2 ----
    gemm_xw2_mfma<<<nt64, 256, 0, stream>>>(hb, wt2, xw2b, N);
    gather2_final<<<(N + 3) / 4, 256, 0, stream>>>(xw2b, row_ptr, es_packed,
                                                   b2, prev, sens, ins,
                                                   out_lsm, out_emb, N);
}

// Round 13
// 442.126 us; speedup vs baseline: 1.2351x; 1.0482x over previous
//
#include <hip/hip_runtime.h>
#include <math.h>

#define F_IN 128
#define HID  128
#define CDIM 64
#define BN_EPS 1e-5f
#define SCAN_CHUNK 1024   // elements per scan block (256 thr x 4)

typedef unsigned int u32;
typedef unsigned short u16;
typedef unsigned long long u64;
typedef __attribute__((ext_vector_type(8))) short bf16x8;   // 8 bf16 = 4 VGPR
typedef __attribute__((ext_vector_type(4))) float f32x4;

// bf16 helpers (RNE)
__device__ __forceinline__ float bf_lo(u32 p) {
    u32 x = p << 16; return __builtin_bit_cast(float, x);
}
__device__ __forceinline__ float bf_hi(u32 p) {
    u32 x = p & 0xffff0000u; return __builtin_bit_cast(float, x);
}
__device__ __forceinline__ u16 f2bf(float f) {
    u32 x = __builtin_bit_cast(u32, f);
    return (u16)((x + 0x7fffu + ((x >> 16) & 1u)) >> 16);
}
__device__ __forceinline__ u32 pack2(float a, float b) {
    return (u32)f2bf(a) | ((u32)f2bf(b) << 16);   // lo = even col
}

// Swizzled LDS fragment load: element k of row r lives at u16 index
// r*128 + (k ^ ((r&7)<<3)). XOR touches bits 3-5 only, so 8-aligned k
// stays 8-aligned -> 16B ds_read_b128. Breaks the 32-way row-stride-256B
// bank conflict (G4 recipe).
__device__ __forceinline__ bf16x8 frag_ld(const u16* lds, int row, int kb) {
    return *(const bf16x8*)&lds[row * 128 + (kb ^ ((row & 7) << 3))];
}

// ---------------------------------------------------------------------------
// wt_prep: build pre-transposed, pre-swizzled bf16 weight images in workspace.
// wt1[c][k] = bf16(W1[k][c]) at u16 idx c*128 + (k ^ ((c&7)<<3))   (32 KB)
// wt2[c][k] = bf16(W2[k][c]) at u16 idx c*128 + (k ^ ((c&7)<<3))   (16 KB)
// ---------------------------------------------------------------------------
__global__ __launch_bounds__(256) void wt_prep(const float* __restrict__ W1,
                                               const float* __restrict__ W2,
                                               u16* __restrict__ wt1,
                                               u16* __restrict__ wt2) {
    int t = blockIdx.x * 256 + threadIdx.x;
    if (t < 128 * 128) {
        int k = t >> 7, c = t & 127;
        wt1[c * 128 + (k ^ ((c & 7) << 3))] = f2bf(W1[t]);   // W1[k*128+c]
    } else if (t < 128 * 128 + 128 * 64) {
        int t2 = t - 128 * 128;
        int k = t2 >> 6, c = t2 & 63;
        wt2[c * 128 + (k ^ ((c & 7) << 3))] = f2bf(W2[t2]);  // W2[k*64+c]
    }
}

// ---------------------------------------------------------------------------
// GEMM1 (MFMA): Y[N,128](bf16) = X[N,128](fp32->bf16) @ W1.
// Transposed formulation D' = Wt * X^T per 16x16 tile (verified R10):
//   each lane packs 4 consecutive output cols of one row into a uint2.
// Block = 256 thr (4 waves), tile = 64 rows x 128 cols, LDS 48 KB (3 blk/CU).
// ---------------------------------------------------------------------------
__global__ __launch_bounds__(256) void gemm_xw1_mfma(const float* __restrict__ X,
                                                     const u16* __restrict__ wt1,
                                                     u32* __restrict__ Yb, int N) {
    __shared__ u16 wl[128 * 128];   // 32 KB (swizzled Wt)
    __shared__ u16 xl[64 * 128];    // 16 KB (swizzled X tile, bf16)
    // stage W once per block (linear copy; image is pre-swizzled)
    for (int i = threadIdx.x; i < 2048; i += 256)
        ((uint4*)wl)[i] = ((const uint4*)wt1)[i];
    const int l  = threadIdx.x & 63;
    const int wv = threadIdx.x >> 6;
    const int r16 = wv * 16;
    const int lr = l & 15;
    const int kq = l >> 4;
    const int ntiles = (N + 63) >> 6;
    for (int tile = blockIdx.x; tile < ntiles; tile += gridDim.x) {
        const int row0 = tile << 6;
        __syncthreads();   // previous iteration's reads done before restage
        // stage X tile 64x128 fp32 -> bf16, swizzled
        for (int i = threadIdx.x; i < 2048; i += 256) {
            int r = i >> 5, c4 = i & 31;       // c4: float4 index (k = c4*4)
            int gr = row0 + r;
            float4 v = make_float4(0.f, 0.f, 0.f, 0.f);
            if (gr < N) v = *(const float4*)&X[(size_t)gr * F_IN + c4 * 4];
            uint2 p;
            p.x = pack2(v.x, v.y);
            p.y = pack2(v.z, v.w);
            *(uint2*)&xl[r * 128 + ((c4 * 4) ^ ((r & 7) << 3))] = p;
        }
        __syncthreads();
        f32x4 acc[8];
        #pragma unroll
        for (int c = 0; c < 8; ++c) acc[c] = (f32x4){0.f, 0.f, 0.f, 0.f};
        #pragma unroll
        for (int k0 = 0; k0 < 128; k0 += 32) {
            int kb = k0 + kq * 8;
            bf16x8 xf = frag_ld(xl, r16 + lr, kb);
            #pragma unroll
            for (int c = 0; c < 8; ++c) {
                bf16x8 wf = frag_ld(wl, c * 16 + lr, kb);
                acc[c] = __builtin_amdgcn_mfma_f32_16x16x32_bf16(wf, xf, acc[c], 0, 0, 0);
            }
        }
        int grow = row0 + r16 + lr;
        if (grow < N) {
            #pragma unroll
            for (int c = 0; c < 8; ++c) {
                uint2 o;
                o.x = pack2(acc[c][0], acc[c][1]);
                o.y = pack2(acc[c][2], acc[c][3]);
                *(uint2*)&Yb[(size_t)grow * 64 + c * 8 + kq * 2] = o;
            }
        }
    }
}

// ---------------------------------------------------------------------------
// GEMM2 (MFMA): Y[N,64](bf16) = H[N,128](bf16) @ W2. Same structure,
// 4 col-tiles, LDS 32 KB (5 blk/CU). H already bf16 -> uint4 copy staging.
// ---------------------------------------------------------------------------
__global__ __launch_bounds__(256) void gemm_xw2_mfma(const u32* __restrict__ Hb,
                                                     const u16* __restrict__ wt2,
                                                     u32* __restrict__ Yb, int N) {
    __shared__ u16 wl[64 * 128];    // 16 KB
    __shared__ u16 xl[64 * 128];    // 16 KB
    for (int i = threadIdx.x; i < 1024; i += 256)
        ((uint4*)wl)[i] = ((const uint4*)wt2)[i];
    const int l  = threadIdx.x & 63;
    const int wv = threadIdx.x >> 6;
    const int r16 = wv * 16;
    const int lr = l & 15;
    const int kq = l >> 4;
    const int ntiles = (N + 63) >> 6;
    for (int tile = blockIdx.x; tile < ntiles; tile += gridDim.x) {
        const int row0 = tile << 6;
        __syncthreads();
        // stage H tile 64 rows x 128 bf16 cols, swizzled (uint4 = 8 bf16)
        for (int i = threadIdx.x; i < 1024; i += 256) {
            int r = i >> 4, c8 = i & 15;       // k = c8*8
            int gr = row0 + r;
            uint4 v = make_uint4(0u, 0u, 0u, 0u);
            if (gr < N) v = *(const uint4*)&Hb[(size_t)gr * 64 + c8 * 4];
            *(uint4*)&xl[r * 128 + ((c8 * 8) ^ ((r & 7) << 3))] = v;
        }
        __syncthreads();
        f32x4 acc[4];
        #pragma unroll
        for (int c = 0; c < 4; ++c) acc[c] = (f32x4){0.f, 0.f, 0.f, 0.f};
        #pragma unroll
        for (int k0 = 0; k0 < 128; k0 += 32) {
            int kb = k0 + kq * 8;
            bf16x8 xf = frag_ld(xl, r16 + lr, kb);
            #pragma unroll
            for (int c = 0; c < 4; ++c) {
                bf16x8 wf = frag_ld(wl, c * 16 + lr, kb);
                acc[c] = __builtin_amdgcn_mfma_f32_16x16x32_bf16(wf, xf, acc[c], 0, 0, 0);
            }
        }
        int grow = row0 + r16 + lr;
        if (grow < N) {
            #pragma unroll
            for (int c = 0; c < 4; ++c) {
                uint2 o;
                o.x = pack2(acc[c][0], acc[c][1]);
                o.y = pack2(acc[c][2], acc[c][3]);
                *(uint2*)&Yb[(size_t)grow * 32 + c * 8 + kq * 2] = o;
            }
        }
    }
}

// ---------------------------------------------------------------------------
// CSR build: hist (+rank) -> scan -> atomic-free fill
// hist: the atomicAdd return value IS the edge's rank within its dst row.
// Storing it (u16; max degree ~45 for E/N=16) makes fill a pure permutation:
// pos = row_ptr[d] + rank[gid] -- no cursor, no slice re-reads, no atomics.
// ---------------------------------------------------------------------------
__global__ __launch_bounds__(256) void hist_kernel(const int* __restrict__ dst,
                                                   int* __restrict__ counts,
                                                   u16* __restrict__ rank, int E) {
    int gid = blockIdx.x * 256 + threadIdx.x;
    int stride = gridDim.x * 256;
    for (; gid < E; gid += stride) {
        int d = __builtin_nontemporal_load(&dst[gid]);
        int r = atomicAdd(&counts[d], 1);
        __builtin_nontemporal_store((u16)r, &rank[gid]);
    }
}

__global__ __launch_bounds__(256) void scan_sums(const int* __restrict__ counts,
                                                 int* __restrict__ bsums, int N) {
    __shared__ int sdata[256];
    int base = blockIdx.x * SCAN_CHUNK + threadIdx.x * 4;
    int t = 0;
    #pragma unroll
    for (int j = 0; j < 4; ++j) { int i = base + j; if (i < N) t += counts[i]; }
    sdata[threadIdx.x] = t; __syncthreads();
    for (int off = 128; off > 0; off >>= 1) {
        if (threadIdx.x < off) sdata[threadIdx.x] += sdata[threadIdx.x + off];
        __syncthreads();
    }
    if (threadIdx.x == 0) bsums[blockIdx.x] = sdata[0];
}

__global__ void scan_offsets(const int* __restrict__ bsums, int* __restrict__ boffs,
                             int nb, int* __restrict__ row_ptr, int N, int E) {
    if (threadIdx.x == 0 && blockIdx.x == 0) {
        int run = 0;
        for (int i = 0; i < nb; ++i) { boffs[i] = run; run += bsums[i]; }
        row_ptr[N] = E;
    }
}

__global__ __launch_bounds__(256) void scan_write(const int* __restrict__ counts,
                                                  const int* __restrict__ boffs,
                                                  int* __restrict__ row_ptr, int N) {
    __shared__ int sdata[256];
    int base = blockIdx.x * SCAN_CHUNK + threadIdx.x * 4;
    int v[4]; int tsum = 0;
    #pragma unroll
    for (int j = 0; j < 4; ++j) {
        int i = base + j;
        v[j] = (i < N) ? counts[i] : 0;
        tsum += v[j];
    }
    sdata[threadIdx.x] = tsum; __syncthreads();
    for (int off = 1; off < 256; off <<= 1) {
        int t = (threadIdx.x >= off) ? sdata[threadIdx.x - off] : 0;
        __syncthreads();
        sdata[threadIdx.x] += t;
        __syncthreads();
    }
    int off0 = sdata[threadIdx.x] - tsum + boffs[blockIdx.x];
    #pragma unroll
    for (int j = 0; j < 4; ++j) {
        int i = base + j;
        if (i < N) { row_ptr[i] = off0; off0 += v[j]; }
    }
}

// ---------------------------------------------------------------------------
// fill: single pass, atomic-free. pos = row_ptr[d] + rank[gid].
// All streams read once, coalesced; es_packed written nontemporal as one
// u64 (uint2* is a HIP class type the builtin rejects; u64* is legal).
// ---------------------------------------------------------------------------
__global__ __launch_bounds__(256) void fill_kernel(const int* __restrict__ src,
                                                   const int* __restrict__ dst,
                                                   const float* __restrict__ w,
                                                   const u16* __restrict__ rank,
                                                   const int* __restrict__ row_ptr,
                                                   u64* __restrict__ es_packed,
                                                   int E) {
    int gid = blockIdx.x * 256 + threadIdx.x;
    int stride = gridDim.x * 256;
    for (; gid < E; gid += stride) {
        int d = __builtin_nontemporal_load(&dst[gid]);
        int pos = row_ptr[d] + (int)__builtin_nontemporal_load(&rank[gid]);
        u64 lo = (u32)__builtin_nontemporal_load(&src[gid]);
        u64 hi = (u64)__builtin_bit_cast(u32, __builtin_nontemporal_load(&w[gid])) << 32;
        __builtin_nontemporal_store(lo | hi, &es_packed[pos]);
    }
}

__global__ void bn_prep(const float* __restrict__ b1, const float* __restrict__ gamma,
                        const float* __restrict__ beta, const float* __restrict__ mean,
                        const float* __restrict__ var, float* __restrict__ scale,
                        float* __restrict__ shift) {
    int f = threadIdx.x;
    if (f < HID) {
        float sc = gamma[f] * rsqrtf(var[f] + BN_EPS);
        scale[f] = sc;
        shift[f] = beta[f] + sc * (b1[f] - mean[f]);
    }
}

// ---------------------------------------------------------------------------
// Gather layer 1 (D=128 bf16): one wave per dst row, four edges/iteration.
// ---------------------------------------------------------------------------
__global__ __launch_bounds__(256) void gather1_kernel(
        const u32* __restrict__ XWb, const int* __restrict__ row_ptr,
        const uint2* __restrict__ es, const float* __restrict__ scale,
        const float* __restrict__ shift, u32* __restrict__ Hb, int N) {
    int r = blockIdx.x * 4 + (threadIdx.x >> 6);
    if (r >= N) return;                     // wave-uniform
    int f = threadIdx.x & 63;
    int q = f >> 4;                         // edge within quad
    int fc = f & 15;                        // col group: bf16 cols 8fc..8fc+7
    int beg = row_ptr[r], end = row_ptr[r + 1];
    float acc[8];
    #pragma unroll
    for (int j = 0; j < 8; ++j) acc[j] = 0.f;
    for (int base = beg; base < end; base += 64) {
        int m = end - base; if (m > 64) m = 64;
        uint2 pk = (f < m) ? es[base + f] : make_uint2(0u, 0u);
        int   se = (int)pk.x;
        float we = __builtin_bit_cast(float, pk.y);
        for (int k = 0; k < m; k += 4) {
            int k0 = k + q;
            int   sk = __shfl(se, k0, 64);
            float wk = __shfl(we, k0, 64);
            uint4 x = *(const uint4*)&XWb[(size_t)sk * 64 + 4 * fc];
            acc[0] = fmaf(bf_lo(x.x), wk, acc[0]);
            acc[1] = fmaf(bf_hi(x.x), wk, acc[1]);
            acc[2] = fmaf(bf_lo(x.y), wk, acc[2]);
            acc[3] = fmaf(bf_hi(x.y), wk, acc[3]);
            acc[4] = fmaf(bf_lo(x.z), wk, acc[4]);
            acc[5] = fmaf(bf_hi(x.z), wk, acc[5]);
            acc[6] = fmaf(bf_lo(x.w), wk, acc[6]);
            acc[7] = fmaf(bf_hi(x.w), wk, acc[7]);
        }
    }
    #pragma unroll
    for (int j = 0; j < 8; ++j) {
        acc[j] += __shfl_xor(acc[j], 16, 64);
        acc[j] += __shfl_xor(acc[j], 32, 64);
    }
    if (q == 0) {
        float4 sc0 = *(const float4*)&scale[8 * fc];
        float4 sc1 = *(const float4*)&scale[8 * fc + 4];
        float4 sh0 = *(const float4*)&shift[8 * fc];
        float4 sh1 = *(const float4*)&shift[8 * fc + 4];
        float h0 = fmaf(acc[0], sc0.x, sh0.x);
        float h1 = fmaf(acc[1], sc0.y, sh0.y);
        float h2 = fmaf(acc[2], sc0.z, sh0.z);
        float h3 = fmaf(acc[3], sc0.w, sh0.w);
        float h4 = fmaf(acc[4], sc1.x, sh1.x);
        float h5 = fmaf(acc[5], sc1.y, sh1.y);
        float h6 = fmaf(acc[6], sc1.z, sh1.z);
        float h7 = fmaf(acc[7], sc1.w, sh1.w);
        uint4 o;
        o.x = pack2(h0 > 0.f ? h0 : 0.f, h1 > 0.f ? h1 : 0.f);
        o.y = pack2(h2 > 0.f ? h2 : 0.f, h3 > 0.f ? h3 : 0.f);
        o.z = pack2(h4 > 0.f ? h4 : 0.f, h5 > 0.f ? h5 : 0.f);
        o.w = pack2(h6 > 0.f ? h6 : 0.f, h7 > 0.f ? h7 : 0.f);
        *(uint4*)&Hb[(size_t)r * 64 + 4 * fc] = o;
    }
}

// ---------------------------------------------------------------------------
// Gather layer 2 (D=64 bf16) + epilogue.
// ---------------------------------------------------------------------------
__global__ __launch_bounds__(256) void gather2_final(
        const u32* __restrict__ XW2b, const int* __restrict__ row_ptr,
        const uint2* __restrict__ es, const float* __restrict__ b2,
        const float* __restrict__ prev, const int* __restrict__ sens,
        const int* __restrict__ ins, float* __restrict__ out_lsm,
        float* __restrict__ out_emb, int N) {
    int r = blockIdx.x * 4 + (threadIdx.x >> 6);
    if (r >= N) return;                     // wave-uniform
    int f = threadIdx.x & 63;
    int q = f >> 4;                         // edge within quad
    int fc = f & 15;                        // col group: bf16 cols 4fc..4fc+3
    int beg = row_ptr[r], end = row_ptr[r + 1];
    float a0 = 0.f, a1 = 0.f, a2 = 0.f, a3 = 0.f;
    for (int base = beg; base < end; base += 64) {
        int m = end - base; if (m > 64) m = 64;
        uint2 pk = (f < m) ? es[base + f] : make_uint2(0u, 0u);
        int   se = (int)pk.x;
        float we = __builtin_bit_cast(float, pk.y);
        for (int k = 0; k < m; k += 4) {
            int k0 = k + q;
            int   sk = __shfl(se, k0, 64);
            float wk = __shfl(we, k0, 64);
            uint2 x = *(const uint2*)&XW2b[(size_t)sk * 32 + 2 * fc];
            a0 = fmaf(bf_lo(x.x), wk, a0);
            a1 = fmaf(bf_hi(x.x), wk, a1);
            a2 = fmaf(bf_lo(x.y), wk, a2);
            a3 = fmaf(bf_hi(x.y), wk, a3);
        }
    }
    a0 += __shfl_xor(a0, 16, 64); a0 += __shfl_xor(a0, 32, 64);
    a1 += __shfl_xor(a1, 16, 64); a1 += __shfl_xor(a1, 32, 64);
    a2 += __shfl_xor(a2, 16, 64); a2 += __shfl_xor(a2, 32, 64);
    a3 += __shfl_xor(a3, 16, 64); a3 += __shfl_xor(a3, 32, 64);

    float4 bb = *(const float4*)&b2[4 * fc];
    float h0 = a0 + bb.x, h1 = a1 + bb.y, h2 = a2 + bb.z, h3 = a3 + bb.w;
    bool s_ = sens[r] != 0;
    bool i_ = ins[r] != 0;
    float4 pv = *(const float4*)&prev[(size_t)r * CDIM + 4 * fc];
    float o0 = (s_ ? h0 : pv.x) + (i_ ? h0 : 0.f);
    float o1 = (s_ ? h1 : pv.y) + (i_ ? h1 : 0.f);
    float o2 = (s_ ? h2 : pv.z) + (i_ ? h2 : 0.f);
    float o3 = (s_ ? h3 : pv.w) + (i_ ? h3 : 0.f);
    // log-softmax over 64 cols: local max/sum of 4, reduce over 16 lanes
    float mm = fmaxf(fmaxf(o0, o1), fmaxf(o2, o3));
    #pragma unroll
    for (int off = 8; off > 0; off >>= 1) mm = fmaxf(mm, __shfl_xor(mm, off, 64));
    float s = expf(o0 - mm) + expf(o1 - mm) + expf(o2 - mm) + expf(o3 - mm);
    #pragma unroll
    for (int off = 8; off > 0; off >>= 1) s += __shfl_xor(s, off, 64);
    float lse = mm + logf(s);
    if (q == 0) {
        *(float4*)&out_lsm[(size_t)r * CDIM + 4 * fc] =
            make_float4(o0 - lse, o1 - lse, o2 - lse, o3 - lse);
        *(float4*)&out_emb[(size_t)r * CDIM + 4 * fc] =
            make_float4(o0, o1, o2, o3);
    }
}

extern "C" void kernel_launch(void* const* d_in, const int* in_sizes, int n_in,
                              void* d_out, int out_size, void* d_ws, size_t ws_size,
                              hipStream_t stream) {
    const float* features = (const float*)d_in[0];
    const int*   esrc     = (const int*)d_in[1];
    const int*   edst     = (const int*)d_in[2];
    const float* ew       = (const float*)d_in[3];
    const float* W1       = (const float*)d_in[4];
    const float* b1       = (const float*)d_in[5];
    const float* gamma1   = (const float*)d_in[6];
    const float* beta1    = (const float*)d_in[7];
    const float* mean1    = (const float*)d_in[8];
    const float* var1     = (const float*)d_in[9];
    const float* W2       = (const float*)d_in[10];
    const float* b2       = (const float*)d_in[11];
    const float* prev     = (const float*)d_in[12];
    const int*   sens     = (const int*)d_in[13];
    const int*   ins      = (const int*)d_in[14];

    const int N = in_sizes[0] / F_IN;
    const int E = in_sizes[1];
    const int nb = (N + SCAN_CHUNK - 1) / SCAN_CHUNK;

    // ---- workspace layout (u32 words) ----
    u16* wt1   = (u16*)d_ws;                         // 128*128 u16 = 8192 u32
    u16* wt2   = wt1 + 128 * 128;                    // 64*128 u16  = 4096 u32
    u32* xw1b  = (u32*)d_ws + 12288;                 // N*64  (128 bf16 cols)
    u32* hb    = xw1b + (size_t)N * 64;              // N*64
    u32* xw2b  = hb + (size_t)N * 64;                // N*32
    u64* es_packed = (u64*)(xw2b + (size_t)N * 32);  // E x 8B (8B-aligned)
    float* scale = (float*)(es_packed + E);          // 128
    float* shift = scale + HID;                      // 128
    int* row_ptr = (int*)(shift + HID);              // N+1
    int* counts  = row_ptr + (N + 1);                // N
    int* bsums   = counts + N;                       // nb
    int* boffs   = bsums + nb;                       // nb
    u16* rank16  = (u16*)(boffs + nb);               // E u16

    float* out_lsm = (float*)d_out;
    float* out_emb = out_lsm + (size_t)N * CDIM;

    // ---- weight prep (bf16, transposed, swizzled) ----
    wt_prep<<<96, 256, 0, stream>>>(W1, W2, wt1, wt2);

    // ---- CSR build ----
    hipMemsetAsync(counts, 0, (size_t)N * sizeof(int), stream);
    hist_kernel<<<(E + 255) / 256, 256, 0, stream>>>(edst, counts, rank16, E);
    scan_sums<<<nb, 256, 0, stream>>>(counts, bsums, N);
    scan_offsets<<<1, 64, 0, stream>>>(bsums, boffs, nb, row_ptr, N, E);
    scan_write<<<nb, 256, 0, stream>>>(counts, boffs, row_ptr, N);
    // atomic-free single-pass fill
    fill_kernel<<<2048, 256, 0, stream>>>(esrc, edst, ew, rank16, row_ptr,
                                          es_packed, E);
    bn_prep<<<1, 128, 0, stream>>>(b1, gamma1, beta1, mean1, var1, scale, shift);

    // ---- layer 1 ----
    const int nt64 = (N + 63) / 64;
    gemm_xw1_mfma<<<nt64, 256, 0, stream>>>(features, wt1, xw1b, N);
    gather1_kernel<<<(N + 3) / 4, 256, 0, stream>>>(xw1b, row_ptr,
                                                    (const uint2*)es_packed,
                                                    scale, shift, hb, N);
    // ---- layer 2 ----
    gemm_xw2_mfma<<<nt64, 256, 0, stream>>>(hb, wt2, xw2b, N);
    gather2_final<<<(N + 3) / 4, 256, 0, stream>>>(xw2b, row_ptr,
                                                   (const uint2*)es_packed,
                                                   b2, prev, sens, ins,
                                                   out_lsm, out_emb, N);
}

// Round 14
// 439.580 us; speedup vs baseline: 1.2423x; 1.0058x over previous
//
#include <hip/hip_runtime.h>
#include <math.h>

#define F_IN 128
#define HID  128
#define CDIM 64
#define BN_EPS 1e-5f
#define SCAN_CHUNK 1024   // elements per scan block (256 thr x 4)

typedef unsigned int u32;
typedef unsigned short u16;
typedef unsigned long long u64;
typedef __attribute__((ext_vector_type(8))) short bf16x8;   // 8 bf16 = 4 VGPR
typedef __attribute__((ext_vector_type(4))) float f32x4;

// bf16 helpers (RNE)
__device__ __forceinline__ float bf_lo(u32 p) {
    u32 x = p << 16; return __builtin_bit_cast(float, x);
}
__device__ __forceinline__ float bf_hi(u32 p) {
    u32 x = p & 0xffff0000u; return __builtin_bit_cast(float, x);
}
__device__ __forceinline__ u16 f2bf(float f) {
    u32 x = __builtin_bit_cast(u32, f);
    return (u16)((x + 0x7fffu + ((x >> 16) & 1u)) >> 16);
}
__device__ __forceinline__ u32 pack2(float a, float b) {
    return (u32)f2bf(a) | ((u32)f2bf(b) << 16);   // lo = even col
}

// Swizzled LDS fragment load: element k of row r lives at u16 index
// r*128 + (k ^ ((r&7)<<3)). XOR touches bits 3-5 only, so 8-aligned k
// stays 8-aligned -> 16B ds_read_b128. Breaks the 32-way row-stride-256B
// bank conflict (G4 recipe).
__device__ __forceinline__ bf16x8 frag_ld(const u16* lds, int row, int kb) {
    return *(const bf16x8*)&lds[row * 128 + (kb ^ ((row & 7) << 3))];
}

// ---------------------------------------------------------------------------
// wt_prep: build pre-transposed, pre-swizzled bf16 weight images in workspace.
// ---------------------------------------------------------------------------
__global__ __launch_bounds__(256) void wt_prep(const float* __restrict__ W1,
                                               const float* __restrict__ W2,
                                               u16* __restrict__ wt1,
                                               u16* __restrict__ wt2) {
    int t = blockIdx.x * 256 + threadIdx.x;
    if (t < 128 * 128) {
        int k = t >> 7, c = t & 127;
        wt1[c * 128 + (k ^ ((c & 7) << 3))] = f2bf(W1[t]);   // W1[k*128+c]
    } else if (t < 128 * 128 + 128 * 64) {
        int t2 = t - 128 * 128;
        int k = t2 >> 6, c = t2 & 63;
        wt2[c * 128 + (k ^ ((c & 7) << 3))] = f2bf(W2[t2]);  // W2[k*64+c]
    }
}

// ---------------------------------------------------------------------------
// GEMM1 (MFMA): Y[N,128](bf16) = X[N,128](fp32->bf16) @ W1.  (verified R10)
// ---------------------------------------------------------------------------
__global__ __launch_bounds__(256) void gemm_xw1_mfma(const float* __restrict__ X,
                                                     const u16* __restrict__ wt1,
                                                     u32* __restrict__ Yb, int N) {
    __shared__ u16 wl[128 * 128];   // 32 KB (swizzled Wt)
    __shared__ u16 xl[64 * 128];    // 16 KB (swizzled X tile, bf16)
    for (int i = threadIdx.x; i < 2048; i += 256)
        ((uint4*)wl)[i] = ((const uint4*)wt1)[i];
    const int l  = threadIdx.x & 63;
    const int wv = threadIdx.x >> 6;
    const int r16 = wv * 16;
    const int lr = l & 15;
    const int kq = l >> 4;
    const int ntiles = (N + 63) >> 6;
    for (int tile = blockIdx.x; tile < ntiles; tile += gridDim.x) {
        const int row0 = tile << 6;
        __syncthreads();
        for (int i = threadIdx.x; i < 2048; i += 256) {
            int r = i >> 5, c4 = i & 31;       // c4: float4 index (k = c4*4)
            int gr = row0 + r;
            float4 v = make_float4(0.f, 0.f, 0.f, 0.f);
            if (gr < N) v = *(const float4*)&X[(size_t)gr * F_IN + c4 * 4];
            uint2 p;
            p.x = pack2(v.x, v.y);
            p.y = pack2(v.z, v.w);
            *(uint2*)&xl[r * 128 + ((c4 * 4) ^ ((r & 7) << 3))] = p;
        }
        __syncthreads();
        f32x4 acc[8];
        #pragma unroll
        for (int c = 0; c < 8; ++c) acc[c] = (f32x4){0.f, 0.f, 0.f, 0.f};
        #pragma unroll
        for (int k0 = 0; k0 < 128; k0 += 32) {
            int kb = k0 + kq * 8;
            bf16x8 xf = frag_ld(xl, r16 + lr, kb);
            #pragma unroll
            for (int c = 0; c < 8; ++c) {
                bf16x8 wf = frag_ld(wl, c * 16 + lr, kb);
                acc[c] = __builtin_amdgcn_mfma_f32_16x16x32_bf16(wf, xf, acc[c], 0, 0, 0);
            }
        }
        int grow = row0 + r16 + lr;
        if (grow < N) {
            #pragma unroll
            for (int c = 0; c < 8; ++c) {
                uint2 o;
                o.x = pack2(acc[c][0], acc[c][1]);
                o.y = pack2(acc[c][2], acc[c][3]);
                *(uint2*)&Yb[(size_t)grow * 64 + c * 8 + kq * 2] = o;
            }
        }
    }
}

// ---------------------------------------------------------------------------
// GEMM2 (MFMA): Y[N,64](bf16) = H[N,128](bf16) @ W2.
// ---------------------------------------------------------------------------
__global__ __launch_bounds__(256) void gemm_xw2_mfma(const u32* __restrict__ Hb,
                                                     const u16* __restrict__ wt2,
                                                     u32* __restrict__ Yb, int N) {
    __shared__ u16 wl[64 * 128];    // 16 KB
    __shared__ u16 xl[64 * 128];    // 16 KB
    for (int i = threadIdx.x; i < 1024; i += 256)
        ((uint4*)wl)[i] = ((const uint4*)wt2)[i];
    const int l  = threadIdx.x & 63;
    const int wv = threadIdx.x >> 6;
    const int r16 = wv * 16;
    const int lr = l & 15;
    const int kq = l >> 4;
    const int ntiles = (N + 63) >> 6;
    for (int tile = blockIdx.x; tile < ntiles; tile += gridDim.x) {
        const int row0 = tile << 6;
        __syncthreads();
        for (int i = threadIdx.x; i < 1024; i += 256) {
            int r = i >> 4, c8 = i & 15;       // k = c8*8
            int gr = row0 + r;
            uint4 v = make_uint4(0u, 0u, 0u, 0u);
            if (gr < N) v = *(const uint4*)&Hb[(size_t)gr * 64 + c8 * 4];
            *(uint4*)&xl[r * 128 + ((c8 * 8) ^ ((r & 7) << 3))] = v;
        }
        __syncthreads();
        f32x4 acc[4];
        #pragma unroll
        for (int c = 0; c < 4; ++c) acc[c] = (f32x4){0.f, 0.f, 0.f, 0.f};
        #pragma unroll
        for (int k0 = 0; k0 < 128; k0 += 32) {
            int kb = k0 + kq * 8;
            bf16x8 xf = frag_ld(xl, r16 + lr, kb);
            #pragma unroll
            for (int c = 0; c < 4; ++c) {
                bf16x8 wf = frag_ld(wl, c * 16 + lr, kb);
                acc[c] = __builtin_amdgcn_mfma_f32_16x16x32_bf16(wf, xf, acc[c], 0, 0, 0);
            }
        }
        int grow = row0 + r16 + lr;
        if (grow < N) {
            #pragma unroll
            for (int c = 0; c < 4; ++c) {
                uint2 o;
                o.x = pack2(acc[c][0], acc[c][1]);
                o.y = pack2(acc[c][2], acc[c][3]);
                *(uint2*)&Yb[(size_t)grow * 32 + c * 8 + kq * 2] = o;
            }
        }
    }
}

// ---------------------------------------------------------------------------
// CSR build: hist (+rank) -> scan -> atomic-free fill  (verified R13)
// ---------------------------------------------------------------------------
__global__ __launch_bounds__(256) void hist_kernel(const int* __restrict__ dst,
                                                   int* __restrict__ counts,
                                                   u16* __restrict__ rank, int E) {
    int gid = blockIdx.x * 256 + threadIdx.x;
    int stride = gridDim.x * 256;
    for (; gid < E; gid += stride) {
        int d = __builtin_nontemporal_load(&dst[gid]);
        int r = atomicAdd(&counts[d], 1);
        __builtin_nontemporal_store((u16)r, &rank[gid]);
    }
}

__global__ __launch_bounds__(256) void scan_sums(const int* __restrict__ counts,
                                                 int* __restrict__ bsums, int N) {
    __shared__ int sdata[256];
    int base = blockIdx.x * SCAN_CHUNK + threadIdx.x * 4;
    int t = 0;
    #pragma unroll
    for (int j = 0; j < 4; ++j) { int i = base + j; if (i < N) t += counts[i]; }
    sdata[threadIdx.x] = t; __syncthreads();
    for (int off = 128; off > 0; off >>= 1) {
        if (threadIdx.x < off) sdata[threadIdx.x] += sdata[threadIdx.x + off];
        __syncthreads();
    }
    if (threadIdx.x == 0) bsums[blockIdx.x] = sdata[0];
}

__global__ void scan_offsets(const int* __restrict__ bsums, int* __restrict__ boffs,
                             int nb, int* __restrict__ row_ptr, int N, int E) {
    if (threadIdx.x == 0 && blockIdx.x == 0) {
        int run = 0;
        for (int i = 0; i < nb; ++i) { boffs[i] = run; run += bsums[i]; }
        row_ptr[N] = E;
    }
}

__global__ __launch_bounds__(256) void scan_write(const int* __restrict__ counts,
                                                  const int* __restrict__ boffs,
                                                  int* __restrict__ row_ptr, int N) {
    __shared__ int sdata[256];
    int base = blockIdx.x * SCAN_CHUNK + threadIdx.x * 4;
    int v[4]; int tsum = 0;
    #pragma unroll
    for (int j = 0; j < 4; ++j) {
        int i = base + j;
        v[j] = (i < N) ? counts[i] : 0;
        tsum += v[j];
    }
    sdata[threadIdx.x] = tsum; __syncthreads();
    for (int off = 1; off < 256; off <<= 1) {
        int t = (threadIdx.x >= off) ? sdata[threadIdx.x - off] : 0;
        __syncthreads();
        sdata[threadIdx.x] += t;
        __syncthreads();
    }
    int off0 = sdata[threadIdx.x] - tsum + boffs[blockIdx.x];
    #pragma unroll
    for (int j = 0; j < 4; ++j) {
        int i = base + j;
        if (i < N) { row_ptr[i] = off0; off0 += v[j]; }
    }
}

// ---------------------------------------------------------------------------
// fill: single pass, atomic-free. pos = row_ptr[d] + rank[gid].
// ---------------------------------------------------------------------------
__global__ __launch_bounds__(256) void fill_kernel(const int* __restrict__ src,
                                                   const int* __restrict__ dst,
                                                   const float* __restrict__ w,
                                                   const u16* __restrict__ rank,
                                                   const int* __restrict__ row_ptr,
                                                   u64* __restrict__ es_packed,
                                                   int E) {
    int gid = blockIdx.x * 256 + threadIdx.x;
    int stride = gridDim.x * 256;
    for (; gid < E; gid += stride) {
        int d = __builtin_nontemporal_load(&dst[gid]);
        int pos = row_ptr[d] + (int)__builtin_nontemporal_load(&rank[gid]);
        u64 lo = (u32)__builtin_nontemporal_load(&src[gid]);
        u64 hi = (u64)__builtin_bit_cast(u32, __builtin_nontemporal_load(&w[gid])) << 32;
        __builtin_nontemporal_store(lo | hi, &es_packed[pos]);
    }
}

__global__ void bn_prep(const float* __restrict__ b1, const float* __restrict__ gamma,
                        const float* __restrict__ beta, const float* __restrict__ mean,
                        const float* __restrict__ var, float* __restrict__ scale,
                        float* __restrict__ shift) {
    int f = threadIdx.x;
    if (f < HID) {
        float sc = gamma[f] * rsqrtf(var[f] + BN_EPS);
        scale[f] = sc;
        shift[f] = beta[f] + sc * (b1[f] - mean[f]);
    }
}

// ---------------------------------------------------------------------------
// Gather layer 1 (D=128 bf16): one wave per dst row, four edges/iteration
// (16 lanes/edge x uint4 = 256 B row; already at max per-lane load width).
// ---------------------------------------------------------------------------
__global__ __launch_bounds__(256) void gather1_kernel(
        const u32* __restrict__ XWb, const int* __restrict__ row_ptr,
        const uint2* __restrict__ es, const float* __restrict__ scale,
        const float* __restrict__ shift, u32* __restrict__ Hb, int N) {
    int r = blockIdx.x * 4 + (threadIdx.x >> 6);
    if (r >= N) return;                     // wave-uniform
    int f = threadIdx.x & 63;
    int q = f >> 4;                         // edge within quad
    int fc = f & 15;                        // col group: bf16 cols 8fc..8fc+7
    int beg = row_ptr[r], end = row_ptr[r + 1];
    float acc[8];
    #pragma unroll
    for (int j = 0; j < 8; ++j) acc[j] = 0.f;
    for (int base = beg; base < end; base += 64) {
        int m = end - base; if (m > 64) m = 64;
        uint2 pk = (f < m) ? es[base + f] : make_uint2(0u, 0u);
        int   se = (int)pk.x;
        float we = __builtin_bit_cast(float, pk.y);
        for (int k = 0; k < m; k += 4) {
            int k0 = k + q;
            int   sk = __shfl(se, k0, 64);
            float wk = __shfl(we, k0, 64);
            uint4 x = *(const uint4*)&XWb[(size_t)sk * 64 + 4 * fc];
            acc[0] = fmaf(bf_lo(x.x), wk, acc[0]);
            acc[1] = fmaf(bf_hi(x.x), wk, acc[1]);
            acc[2] = fmaf(bf_lo(x.y), wk, acc[2]);
            acc[3] = fmaf(bf_hi(x.y), wk, acc[3]);
            acc[4] = fmaf(bf_lo(x.z), wk, acc[4]);
            acc[5] = fmaf(bf_hi(x.z), wk, acc[5]);
            acc[6] = fmaf(bf_lo(x.w), wk, acc[6]);
            acc[7] = fmaf(bf_hi(x.w), wk, acc[7]);
        }
    }
    #pragma unroll
    for (int j = 0; j < 8; ++j) {
        acc[j] += __shfl_xor(acc[j], 16, 64);
        acc[j] += __shfl_xor(acc[j], 32, 64);
    }
    if (q == 0) {
        float4 sc0 = *(const float4*)&scale[8 * fc];
        float4 sc1 = *(const float4*)&scale[8 * fc + 4];
        float4 sh0 = *(const float4*)&shift[8 * fc];
        float4 sh1 = *(const float4*)&shift[8 * fc + 4];
        float h0 = fmaf(acc[0], sc0.x, sh0.x);
        float h1 = fmaf(acc[1], sc0.y, sh0.y);
        float h2 = fmaf(acc[2], sc0.z, sh0.z);
        float h3 = fmaf(acc[3], sc0.w, sh0.w);
        float h4 = fmaf(acc[4], sc1.x, sh1.x);
        float h5 = fmaf(acc[5], sc1.y, sh1.y);
        float h6 = fmaf(acc[6], sc1.z, sh1.z);
        float h7 = fmaf(acc[7], sc1.w, sh1.w);
        uint4 o;
        o.x = pack2(h0 > 0.f ? h0 : 0.f, h1 > 0.f ? h1 : 0.f);
        o.y = pack2(h2 > 0.f ? h2 : 0.f, h3 > 0.f ? h3 : 0.f);
        o.z = pack2(h4 > 0.f ? h4 : 0.f, h5 > 0.f ? h5 : 0.f);
        o.w = pack2(h6 > 0.f ? h6 : 0.f, h7 > 0.f ? h7 : 0.f);
        *(uint4*)&Hb[(size_t)r * 64 + 4 * fc] = o;
    }
}

// ---------------------------------------------------------------------------
// Gather layer 2 (D=64 bf16) + epilogue: WIDENED to EIGHT edges/iteration.
// 8 lanes/edge x uint4 (16 B) = 128 B row. q = f>>3 (edge in octet),
// fc = f&7 (cols 8fc..8fc+7). Halves inner iterations + shfl/edge vs the
// old 16-lane x uint2 layout; same bytes. Reduce over q: shfl_xor(8,16,32);
// softmax across fc lanes: shfl_xor(4,2,1). q==0 (8 lanes) writes 256 B/row.
// ---------------------------------------------------------------------------
__global__ __launch_bounds__(256) void gather2_final(
        const u32* __restrict__ XW2b, const int* __restrict__ row_ptr,
        const uint2* __restrict__ es, const float* __restrict__ b2,
        const float* __restrict__ prev, const int* __restrict__ sens,
        const int* __restrict__ ins, float* __restrict__ out_lsm,
        float* __restrict__ out_emb, int N) {
    int r = blockIdx.x * 4 + (threadIdx.x >> 6);
    if (r >= N) return;                     // wave-uniform
    int f = threadIdx.x & 63;
    int q = f >> 3;                         // edge within octet (0..7)
    int fc = f & 7;                         // col group: bf16 cols 8fc..8fc+7
    int beg = row_ptr[r], end = row_ptr[r + 1];
    float a[8];
    #pragma unroll
    for (int j = 0; j < 8; ++j) a[j] = 0.f;
    for (int base = beg; base < end; base += 64) {
        int m = end - base; if (m > 64) m = 64;
        uint2 pk = (f < m) ? es[base + f] : make_uint2(0u, 0u);
        int   se = (int)pk.x;
        float we = __builtin_bit_cast(float, pk.y);
        for (int k = 0; k < m; k += 8) {
            int k0 = k + q;                 // k0 <= 56+7 = 63: shfl always valid;
            int   sk = __shfl(se, k0, 64);  // k0 >= m lanes carry we=0 -> no-op
            float wk = __shfl(we, k0, 64);
            uint4 x = *(const uint4*)&XW2b[(size_t)sk * 32 + 4 * fc];
            a[0] = fmaf(bf_lo(x.x), wk, a[0]);
            a[1] = fmaf(bf_hi(x.x), wk, a[1]);
            a[2] = fmaf(bf_lo(x.y), wk, a[2]);
            a[3] = fmaf(bf_hi(x.y), wk, a[3]);
            a[4] = fmaf(bf_lo(x.z), wk, a[4]);
            a[5] = fmaf(bf_hi(x.z), wk, a[5]);
            a[6] = fmaf(bf_lo(x.w), wk, a[6]);
            a[7] = fmaf(bf_hi(x.w), wk, a[7]);
        }
    }
    #pragma unroll
    for (int j = 0; j < 8; ++j) {
        a[j] += __shfl_xor(a[j], 8, 64);
        a[j] += __shfl_xor(a[j], 16, 64);
        a[j] += __shfl_xor(a[j], 32, 64);
    }

    float4 bb0 = *(const float4*)&b2[8 * fc];
    float4 bb1 = *(const float4*)&b2[8 * fc + 4];
    float h[8];
    h[0] = a[0] + bb0.x; h[1] = a[1] + bb0.y;
    h[2] = a[2] + bb0.z; h[3] = a[3] + bb0.w;
    h[4] = a[4] + bb1.x; h[5] = a[5] + bb1.y;
    h[6] = a[6] + bb1.z; h[7] = a[7] + bb1.w;
    bool s_ = sens[r] != 0;
    bool i_ = ins[r] != 0;
    float4 pv0 = *(const float4*)&prev[(size_t)r * CDIM + 8 * fc];
    float4 pv1 = *(const float4*)&prev[(size_t)r * CDIM + 8 * fc + 4];
    float pvv[8] = {pv0.x, pv0.y, pv0.z, pv0.w, pv1.x, pv1.y, pv1.z, pv1.w};
    float o[8];
    #pragma unroll
    for (int j = 0; j < 8; ++j)
        o[j] = (s_ ? h[j] : pvv[j]) + (i_ ? h[j] : 0.f);
    // log-softmax over 64 cols: local max/sum of 8, reduce across fc lanes
    float mm = o[0];
    #pragma unroll
    for (int j = 1; j < 8; ++j) mm = fmaxf(mm, o[j]);
    #pragma unroll
    for (int off = 4; off > 0; off >>= 1) mm = fmaxf(mm, __shfl_xor(mm, off, 64));
    float s = 0.f;
    #pragma unroll
    for (int j = 0; j < 8; ++j) s += expf(o[j] - mm);
    #pragma unroll
    for (int off = 4; off > 0; off >>= 1) s += __shfl_xor(s, off, 64);
    float lse = mm + logf(s);
    if (q == 0) {
        *(float4*)&out_lsm[(size_t)r * CDIM + 8 * fc] =
            make_float4(o[0] - lse, o[1] - lse, o[2] - lse, o[3] - lse);
        *(float4*)&out_lsm[(size_t)r * CDIM + 8 * fc + 4] =
            make_float4(o[4] - lse, o[5] - lse, o[6] - lse, o[7] - lse);
        *(float4*)&out_emb[(size_t)r * CDIM + 8 * fc] =
            make_float4(o[0], o[1], o[2], o[3]);
        *(float4*)&out_emb[(size_t)r * CDIM + 8 * fc + 4] =
            make_float4(o[4], o[5], o[6], o[7]);
    }
}

extern "C" void kernel_launch(void* const* d_in, const int* in_sizes, int n_in,
                              void* d_out, int out_size, void* d_ws, size_t ws_size,
                              hipStream_t stream) {
    const float* features = (const float*)d_in[0];
    const int*   esrc     = (const int*)d_in[1];
    const int*   edst     = (const int*)d_in[2];
    const float* ew       = (const float*)d_in[3];
    const float* W1       = (const float*)d_in[4];
    const float* b1       = (const float*)d_in[5];
    const float* gamma1   = (const float*)d_in[6];
    const float* beta1    = (const float*)d_in[7];
    const float* mean1    = (const float*)d_in[8];
    const float* var1     = (const float*)d_in[9];
    const float* W2       = (const float*)d_in[10];
    const float* b2       = (const float*)d_in[11];
    const float* prev     = (const float*)d_in[12];
    const int*   sens     = (const int*)d_in[13];
    const int*   ins      = (const int*)d_in[14];

    const int N = in_sizes[0] / F_IN;
    const int E = in_sizes[1];
    const int nb = (N + SCAN_CHUNK - 1) / SCAN_CHUNK;

    // ---- workspace layout (u32 words) ----
    u16* wt1   = (u16*)d_ws;                         // 128*128 u16 = 8192 u32
    u16* wt2   = wt1 + 128 * 128;                    // 64*128 u16  = 4096 u32
    u32* xw1b  = (u32*)d_ws + 12288;                 // N*64  (128 bf16 cols)
    u32* hb    = xw1b + (size_t)N * 64;              // N*64
    u32* xw2b  = hb + (size_t)N * 64;                // N*32
    u64* es_packed = (u64*)(xw2b + (size_t)N * 32);  // E x 8B (8B-aligned)
    float* scale = (float*)(es_packed + E);          // 128
    float* shift = scale + HID;                      // 128
    int* row_ptr = (int*)(shift + HID);              // N+1
    int* counts  = row_ptr + (N + 1);                // N
    int* bsums   = counts + N;                       // nb
    int* boffs   = bsums + nb;                       // nb
    u16* rank16  = (u16*)(boffs + nb);               // E u16

    float* out_lsm = (float*)d_out;
    float* out_emb = out_lsm + (size_t)N * CDIM;

    // ---- weight prep (bf16, transposed, swizzled) ----
    wt_prep<<<96, 256, 0, stream>>>(W1, W2, wt1, wt2);

    // ---- CSR build ----
    hipMemsetAsync(counts, 0, (size_t)N * sizeof(int), stream);
    hist_kernel<<<(E + 255) / 256, 256, 0, stream>>>(edst, counts, rank16, E);
    scan_sums<<<nb, 256, 0, stream>>>(counts, bsums, N);
    scan_offsets<<<1, 64, 0, stream>>>(bsums, boffs, nb, row_ptr, N, E);
    scan_write<<<nb, 256, 0, stream>>>(counts, boffs, row_ptr, N);
    // atomic-free single-pass fill
    fill_kernel<<<2048, 256, 0, stream>>>(esrc, edst, ew, rank16, row_ptr,
                                          es_packed, E);
    bn_prep<<<1, 128, 0, stream>>>(b1, gamma1, beta1, mean1, var1, scale, shift);

    // ---- layer 1 ----
    const int nt64 = (N + 63) / 64;
    gemm_xw1_mfma<<<nt64, 256, 0, stream>>>(features, wt1, xw1b, N);
    gather1_kernel<<<(N + 3) / 4, 256, 0, stream>>>(xw1b, row_ptr,
                                                    (const uint2*)es_packed,
                                                    scale, shift, hb, N);
    // ---- layer 2 ----
    gemm_xw2_mfma<<<nt64, 256, 0, stream>>>(hb, wt2, xw2b, N);
    gather2_final<<<(N + 3) / 4, 256, 0, stream>>>(xw2b, row_ptr,
                                                   (const uint2*)es_packed,
                                                   b2, prev, sens, ins,
                                                   out_lsm, out_emb, N);
}

// Round 16
// 435.753 us; speedup vs baseline: 1.2532x; 1.0088x over previous
//
#include <hip/hip_runtime.h>
#include <math.h>

#define F_IN 128
#define HID  128
#define CDIM 64
#define BN_EPS 1e-5f
#define SCAN_CHUNK 1024   // elements per scan block (256 thr x 4)

typedef unsigned int u32;
typedef unsigned short u16;
typedef unsigned long long u64;
typedef __attribute__((ext_vector_type(8))) short bf16x8;   // 8 bf16 = 4 VGPR
typedef __attribute__((ext_vector_type(4))) float f32x4;
typedef __attribute__((ext_vector_type(2))) float f32x2;    // -> v_pk_fma_f32

// bf16 helpers (RNE)
__device__ __forceinline__ float bf_lo(u32 p) {
    u32 x = p << 16; return __builtin_bit_cast(float, x);
}
__device__ __forceinline__ float bf_hi(u32 p) {
    u32 x = p & 0xffff0000u; return __builtin_bit_cast(float, x);
}
// unpack u32 (2 bf16) -> f32x2 {even col, odd col}
__device__ __forceinline__ f32x2 bf2(u32 p) {
    return (f32x2){bf_lo(p), bf_hi(p)};
}
__device__ __forceinline__ u16 f2bf(float f) {
    u32 x = __builtin_bit_cast(u32, f);
    return (u16)((x + 0x7fffu + ((x >> 16) & 1u)) >> 16);
}
__device__ __forceinline__ u32 pack2(float a, float b) {
    return (u32)f2bf(a) | ((u32)f2bf(b) << 16);   // lo = even col
}

// Swizzled LDS fragment load (G4 recipe, verified R10).
__device__ __forceinline__ bf16x8 frag_ld(const u16* lds, int row, int kb) {
    return *(const bf16x8*)&lds[row * 128 + (kb ^ ((row & 7) << 3))];
}

// ---------------------------------------------------------------------------
// prep_kernel: fuses wt_prep + bn_prep + counts-zeroing (saves 2 dispatches).
// wt images: pre-transposed, pre-swizzled bf16 (verified R10).
// ---------------------------------------------------------------------------
__global__ __launch_bounds__(256) void prep_kernel(
        const float* __restrict__ W1, const float* __restrict__ W2,
        u16* __restrict__ wt1, u16* __restrict__ wt2,
        const float* __restrict__ b1, const float* __restrict__ gamma,
        const float* __restrict__ beta, const float* __restrict__ mean,
        const float* __restrict__ var, float* __restrict__ scale,
        float* __restrict__ shift, int* __restrict__ counts, int N) {
    int t = blockIdx.x * 256 + threadIdx.x;
    if (t < 128 * 128) {
        int k = t >> 7, c = t & 127;
        wt1[c * 128 + (k ^ ((c & 7) << 3))] = f2bf(W1[t]);   // W1[k*128+c]
    } else if (t < 128 * 128 + 128 * 64) {
        int t2 = t - 128 * 128;
        int k = t2 >> 6, c = t2 & 63;
        wt2[c * 128 + (k ^ ((c & 7) << 3))] = f2bf(W2[t2]);  // W2[k*64+c]
    }
    if (t < HID) {
        float sc = gamma[t] * rsqrtf(var[t] + BN_EPS);
        scale[t] = sc;
        shift[t] = beta[t] + sc * (b1[t] - mean[t]);
    }
    for (int i = t; i < N; i += gridDim.x * 256) counts[i] = 0;
}

// ---------------------------------------------------------------------------
// GEMM1 (MFMA): Y[N,128](bf16) = X[N,128](fp32->bf16) @ W1.  (verified R10)
// ---------------------------------------------------------------------------
__global__ __launch_bounds__(256) void gemm_xw1_mfma(const float* __restrict__ X,
                                                     const u16* __restrict__ wt1,
                                                     u32* __restrict__ Yb, int N) {
    __shared__ u16 wl[128 * 128];   // 32 KB (swizzled Wt)
    __shared__ u16 xl[64 * 128];    // 16 KB (swizzled X tile, bf16)
    for (int i = threadIdx.x; i < 2048; i += 256)
        ((uint4*)wl)[i] = ((const uint4*)wt1)[i];
    const int l  = threadIdx.x & 63;
    const int wv = threadIdx.x >> 6;
    const int r16 = wv * 16;
    const int lr = l & 15;
    const int kq = l >> 4;
    const int ntiles = (N + 63) >> 6;
    for (int tile = blockIdx.x; tile < ntiles; tile += gridDim.x) {
        const int row0 = tile << 6;
        __syncthreads();
        for (int i = threadIdx.x; i < 2048; i += 256) {
            int r = i >> 5, c4 = i & 31;       // c4: float4 index (k = c4*4)
            int gr = row0 + r;
            float4 v = make_float4(0.f, 0.f, 0.f, 0.f);
            if (gr < N) v = *(const float4*)&X[(size_t)gr * F_IN + c4 * 4];
            uint2 p;
            p.x = pack2(v.x, v.y);
            p.y = pack2(v.z, v.w);
            *(uint2*)&xl[r * 128 + ((c4 * 4) ^ ((r & 7) << 3))] = p;
        }
        __syncthreads();
        f32x4 acc[8];
        #pragma unroll
        for (int c = 0; c < 8; ++c) acc[c] = (f32x4){0.f, 0.f, 0.f, 0.f};
        #pragma unroll
        for (int k0 = 0; k0 < 128; k0 += 32) {
            int kb = k0 + kq * 8;
            bf16x8 xf = frag_ld(xl, r16 + lr, kb);
            #pragma unroll
            for (int c = 0; c < 8; ++c) {
                bf16x8 wf = frag_ld(wl, c * 16 + lr, kb);
                acc[c] = __builtin_amdgcn_mfma_f32_16x16x32_bf16(wf, xf, acc[c], 0, 0, 0);
            }
        }
        int grow = row0 + r16 + lr;
        if (grow < N) {
            #pragma unroll
            for (int c = 0; c < 8; ++c) {
                uint2 o;
                o.x = pack2(acc[c][0], acc[c][1]);
                o.y = pack2(acc[c][2], acc[c][3]);
                *(uint2*)&Yb[(size_t)grow * 64 + c * 8 + kq * 2] = o;
            }
        }
    }
}

// ---------------------------------------------------------------------------
// GEMM2 (MFMA): Y[N,64](bf16) = H[N,128](bf16) @ W2.
// ---------------------------------------------------------------------------
__global__ __launch_bounds__(256) void gemm_xw2_mfma(const u32* __restrict__ Hb,
                                                     const u16* __restrict__ wt2,
                                                     u32* __restrict__ Yb, int N) {
    __shared__ u16 wl[64 * 128];    // 16 KB
    __shared__ u16 xl[64 * 128];    // 16 KB
    for (int i = threadIdx.x; i < 1024; i += 256)
        ((uint4*)wl)[i] = ((const uint4*)wt2)[i];
    const int l  = threadIdx.x & 63;
    const int wv = threadIdx.x >> 6;
    const int r16 = wv * 16;
    const int lr = l & 15;
    const int kq = l >> 4;
    const int ntiles = (N + 63) >> 6;
    for (int tile = blockIdx.x; tile < ntiles; tile += gridDim.x) {
        const int row0 = tile << 6;
        __syncthreads();
        for (int i = threadIdx.x; i < 1024; i += 256) {
            int r = i >> 4, c8 = i & 15;       // k = c8*8
            int gr = row0 + r;
            uint4 v = make_uint4(0u, 0u, 0u, 0u);
            if (gr < N) v = *(const uint4*)&Hb[(size_t)gr * 64 + c8 * 4];
            *(uint4*)&xl[r * 128 + ((c8 * 8) ^ ((r & 7) << 3))] = v;
        }
        __syncthreads();
        f32x4 acc[4];
        #pragma unroll
        for (int c = 0; c < 4; ++c) acc[c] = (f32x4){0.f, 0.f, 0.f, 0.f};
        #pragma unroll
        for (int k0 = 0; k0 < 128; k0 += 32) {
            int kb = k0 + kq * 8;
            bf16x8 xf = frag_ld(xl, r16 + lr, kb);
            #pragma unroll
            for (int c = 0; c < 4; ++c) {
                bf16x8 wf = frag_ld(wl, c * 16 + lr, kb);
                acc[c] = __builtin_amdgcn_mfma_f32_16x16x32_bf16(wf, xf, acc[c], 0, 0, 0);
            }
        }
        int grow = row0 + r16 + lr;
        if (grow < N) {
            #pragma unroll
            for (int c = 0; c < 4; ++c) {
                uint2 o;
                o.x = pack2(acc[c][0], acc[c][1]);
                o.y = pack2(acc[c][2], acc[c][3]);
                *(uint2*)&Yb[(size_t)grow * 32 + c * 8 + kq * 2] = o;
            }
        }
    }
}

// ---------------------------------------------------------------------------
// CSR build: hist (+rank) -> scan -> atomic-free fill  (verified R13)
// ---------------------------------------------------------------------------
__global__ __launch_bounds__(256) void hist_kernel(const int* __restrict__ dst,
                                                   int* __restrict__ counts,
                                                   u16* __restrict__ rank, int E) {
    int gid = blockIdx.x * 256 + threadIdx.x;
    int stride = gridDim.x * 256;
    for (; gid < E; gid += stride) {
        int d = __builtin_nontemporal_load(&dst[gid]);
        int r = atomicAdd(&counts[d], 1);
        __builtin_nontemporal_store((u16)r, &rank[gid]);
    }
}

__global__ __launch_bounds__(256) void scan_sums(const int* __restrict__ counts,
                                                 int* __restrict__ bsums, int N) {
    __shared__ int sdata[256];
    int base = blockIdx.x * SCAN_CHUNK + threadIdx.x * 4;
    int t = 0;
    #pragma unroll
    for (int j = 0; j < 4; ++j) { int i = base + j; if (i < N) t += counts[i]; }
    sdata[threadIdx.x] = t; __syncthreads();
    for (int off = 128; off > 0; off >>= 1) {
        if (threadIdx.x < off) sdata[threadIdx.x] += sdata[threadIdx.x + off];
        __syncthreads();
    }
    if (threadIdx.x == 0) bsums[blockIdx.x] = sdata[0];
}

__global__ void scan_offsets(const int* __restrict__ bsums, int* __restrict__ boffs,
                             int nb, int* __restrict__ row_ptr, int N, int E) {
    if (threadIdx.x == 0 && blockIdx.x == 0) {
        int run = 0;
        for (int i = 0; i < nb; ++i) { boffs[i] = run; run += bsums[i]; }
        row_ptr[N] = E;
    }
}

__global__ __launch_bounds__(256) void scan_write(const int* __restrict__ counts,
                                                  const int* __restrict__ boffs,
                                                  int* __restrict__ row_ptr, int N) {
    __shared__ int sdata[256];
    int base = blockIdx.x * SCAN_CHUNK + threadIdx.x * 4;
    int v[4]; int tsum = 0;
    #pragma unroll
    for (int j = 0; j < 4; ++j) {
        int i = base + j;
        v[j] = (i < N) ? counts[i] : 0;
        tsum += v[j];
    }
    sdata[threadIdx.x] = tsum; __syncthreads();
    for (int off = 1; off < 256; off <<= 1) {
        int t = (threadIdx.x >= off) ? sdata[threadIdx.x - off] : 0;
        __syncthreads();
        sdata[threadIdx.x] += t;
        __syncthreads();
    }
    int off0 = sdata[threadIdx.x] - tsum + boffs[blockIdx.x];
    #pragma unroll
    for (int j = 0; j < 4; ++j) {
        int i = base + j;
        if (i < N) { row_ptr[i] = off0; off0 += v[j]; }
    }
}

// ---------------------------------------------------------------------------
// fill: single pass, atomic-free. pos = row_ptr[d] + rank[gid].
// ---------------------------------------------------------------------------
__global__ __launch_bounds__(256) void fill_kernel(const int* __restrict__ src,
                                                   const int* __restrict__ dst,
                                                   const float* __restrict__ w,
                                                   const u16* __restrict__ rank,
                                                   const int* __restrict__ row_ptr,
                                                   u64* __restrict__ es_packed,
                                                   int E) {
    int gid = blockIdx.x * 256 + threadIdx.x;
    int stride = gridDim.x * 256;
    for (; gid < E; gid += stride) {
        int d = __builtin_nontemporal_load(&dst[gid]);
        int pos = row_ptr[d] + (int)__builtin_nontemporal_load(&rank[gid]);
        u64 lo = (u32)__builtin_nontemporal_load(&src[gid]);
        u64 hi = (u64)__builtin_bit_cast(u32, __builtin_nontemporal_load(&w[gid])) << 32;
        __builtin_nontemporal_store(lo | hi, &es_packed[pos]);
    }
}

// ---------------------------------------------------------------------------
// Gather layer 1 (D=128 bf16): one wave per dst row, 4 edges/iter
// (16 lanes/edge x uint4). Hot loop vectorized to f32x2 -> v_pk_fma_f32.
// ---------------------------------------------------------------------------
__global__ __launch_bounds__(256) void gather1_kernel(
        const u32* __restrict__ XWb, const int* __restrict__ row_ptr,
        const uint2* __restrict__ es, const float* __restrict__ scale,
        const float* __restrict__ shift, u32* __restrict__ Hb, int N) {
    int r = blockIdx.x * 4 + (threadIdx.x >> 6);
    if (r >= N) return;                     // wave-uniform
    int f = threadIdx.x & 63;
    int q = f >> 4;                         // edge within quad
    int fc = f & 15;                        // col group: bf16 cols 8fc..8fc+7
    int beg = row_ptr[r], end = row_ptr[r + 1];
    f32x2 A[4];
    #pragma unroll
    for (int j = 0; j < 4; ++j) A[j] = (f32x2){0.f, 0.f};
    for (int base = beg; base < end; base += 64) {
        int m = end - base; if (m > 64) m = 64;
        uint2 pk = (f < m) ? es[base + f] : make_uint2(0u, 0u);
        int   se = (int)pk.x;
        float we = __builtin_bit_cast(float, pk.y);
        for (int k = 0; k < m; k += 4) {
            int k0 = k + q;
            int   sk = __shfl(se, k0, 64);
            float wk = __shfl(we, k0, 64);
            f32x2 w2 = (f32x2){wk, wk};
            uint4 x = *(const uint4*)&XWb[(size_t)sk * 64 + 4 * fc];
            A[0] = __builtin_elementwise_fma(bf2(x.x), w2, A[0]);
            A[1] = __builtin_elementwise_fma(bf2(x.y), w2, A[1]);
            A[2] = __builtin_elementwise_fma(bf2(x.z), w2, A[2]);
            A[3] = __builtin_elementwise_fma(bf2(x.w), w2, A[3]);
        }
    }
    float acc[8] = {A[0][0], A[0][1], A[1][0], A[1][1],
                    A[2][0], A[2][1], A[3][0], A[3][1]};
    #pragma unroll
    for (int j = 0; j < 8; ++j) {
        acc[j] += __shfl_xor(acc[j], 16, 64);
        acc[j] += __shfl_xor(acc[j], 32, 64);
    }
    if (q == 0) {
        float4 sc0 = *(const float4*)&scale[8 * fc];
        float4 sc1 = *(const float4*)&scale[8 * fc + 4];
        float4 sh0 = *(const float4*)&shift[8 * fc];
        float4 sh1 = *(const float4*)&shift[8 * fc + 4];
        float h0 = fmaf(acc[0], sc0.x, sh0.x);
        float h1 = fmaf(acc[1], sc0.y, sh0.y);
        float h2 = fmaf(acc[2], sc0.z, sh0.z);
        float h3 = fmaf(acc[3], sc0.w, sh0.w);
        float h4 = fmaf(acc[4], sc1.x, sh1.x);
        float h5 = fmaf(acc[5], sc1.y, sh1.y);
        float h6 = fmaf(acc[6], sc1.z, sh1.z);
        float h7 = fmaf(acc[7], sc1.w, sh1.w);
        uint4 o;
        o.x = pack2(h0 > 0.f ? h0 : 0.f, h1 > 0.f ? h1 : 0.f);
        o.y = pack2(h2 > 0.f ? h2 : 0.f, h3 > 0.f ? h3 : 0.f);
        o.z = pack2(h4 > 0.f ? h4 : 0.f, h5 > 0.f ? h5 : 0.f);
        o.w = pack2(h6 > 0.f ? h6 : 0.f, h7 > 0.f ? h7 : 0.f);
        *(uint4*)&Hb[(size_t)r * 64 + 4 * fc] = o;
    }
}

// ---------------------------------------------------------------------------
// Gather layer 2 (D=64 bf16) + epilogue: 8 edges/iter (8 lanes/edge x uint4),
// hot loop vectorized to f32x2 -> v_pk_fma_f32.  (layout verified R14)
// ---------------------------------------------------------------------------
__global__ __launch_bounds__(256) void gather2_final(
        const u32* __restrict__ XW2b, const int* __restrict__ row_ptr,
        const uint2* __restrict__ es, const float* __restrict__ b2,
        const float* __restrict__ prev, const int* __restrict__ sens,
        const int* __restrict__ ins, float* __restrict__ out_lsm,
        float* __restrict__ out_emb, int N) {
    int r = blockIdx.x * 4 + (threadIdx.x >> 6);
    if (r >= N) return;                     // wave-uniform
    int f = threadIdx.x & 63;
    int q = f >> 3;                         // edge within octet (0..7)
    int fc = f & 7;                         // col group: bf16 cols 8fc..8fc+7
    int beg = row_ptr[r], end = row_ptr[r + 1];
    f32x2 A[4];
    #pragma unroll
    for (int j = 0; j < 4; ++j) A[j] = (f32x2){0.f, 0.f};
    for (int base = beg; base < end; base += 64) {
        int m = end - base; if (m > 64) m = 64;
        uint2 pk = (f < m) ? es[base + f] : make_uint2(0u, 0u);
        int   se = (int)pk.x;
        float we = __builtin_bit_cast(float, pk.y);
        for (int k = 0; k < m; k += 8) {
            int k0 = k + q;                 // lanes with k0 >= m carry we=0
            int   sk = __shfl(se, k0, 64);
            float wk = __shfl(we, k0, 64);
            f32x2 w2 = (f32x2){wk, wk};
            uint4 x = *(const uint4*)&XW2b[(size_t)sk * 32 + 4 * fc];
            A[0] = __builtin_elementwise_fma(bf2(x.x), w2, A[0]);
            A[1] = __builtin_elementwise_fma(bf2(x.y), w2, A[1]);
            A[2] = __builtin_elementwise_fma(bf2(x.z), w2, A[2]);
            A[3] = __builtin_elementwise_fma(bf2(x.w), w2, A[3]);
        }
    }
    float a[8] = {A[0][0], A[0][1], A[1][0], A[1][1],
                  A[2][0], A[2][1], A[3][0], A[3][1]};
    #pragma unroll
    for (int j = 0; j < 8; ++j) {
        a[j] += __shfl_xor(a[j], 8, 64);
        a[j] += __shfl_xor(a[j], 16, 64);
        a[j] += __shfl_xor(a[j], 32, 64);
    }

    float4 bb0 = *(const float4*)&b2[8 * fc];
    float4 bb1 = *(const float4*)&b2[8 * fc + 4];
    float h[8];
    h[0] = a[0] + bb0.x; h[1] = a[1] + bb0.y;
    h[2] = a[2] + bb0.z; h[3] = a[3] + bb0.w;
    h[4] = a[4] + bb1.x; h[5] = a[5] + bb1.y;
    h[6] = a[6] + bb1.z; h[7] = a[7] + bb1.w;
    bool s_ = sens[r] != 0;
    bool i_ = ins[r] != 0;
    float4 pv0 = *(const float4*)&prev[(size_t)r * CDIM + 8 * fc];
    float4 pv1 = *(const float4*)&prev[(size_t)r * CDIM + 8 * fc + 4];
    float pvv[8] = {pv0.x, pv0.y, pv0.z, pv0.w, pv1.x, pv1.y, pv1.z, pv1.w};
    float o[8];
    #pragma unroll
    for (int j = 0; j < 8; ++j)
        o[j] = (s_ ? h[j] : pvv[j]) + (i_ ? h[j] : 0.f);
    // log-softmax over 64 cols: local max/sum of 8, reduce across fc lanes
    float mm = o[0];
    #pragma unroll
    for (int j = 1; j < 8; ++j) mm = fmaxf(mm, o[j]);
    #pragma unroll
    for (int off = 4; off > 0; off >>= 1) mm = fmaxf(mm, __shfl_xor(mm, off, 64));
    float s = 0.f;
    #pragma unroll
    for (int j = 0; j < 8; ++j) s += expf(o[j] - mm);
    #pragma unroll
    for (int off = 4; off > 0; off >>= 1) s += __shfl_xor(s, off, 64);
    float lse = mm + logf(s);
    if (q == 0) {
        *(float4*)&out_lsm[(size_t)r * CDIM + 8 * fc] =
            make_float4(o[0] - lse, o[1] - lse, o[2] - lse, o[3] - lse);
        *(float4*)&out_lsm[(size_t)r * CDIM + 8 * fc + 4] =
            make_float4(o[4] - lse, o[5] - lse, o[6] - lse, o[7] - lse);
        *(float4*)&out_emb[(size_t)r * CDIM + 8 * fc] =
            make_float4(o[0], o[1], o[2], o[3]);
        *(float4*)&out_emb[(size_t)r * CDIM + 8 * fc + 4] =
            make_float4(o[4], o[5], o[6], o[7]);
    }
}

extern "C" void kernel_launch(void* const* d_in, const int* in_sizes, int n_in,
                              void* d_out, int out_size, void* d_ws, size_t ws_size,
                              hipStream_t stream) {
    const float* features = (const float*)d_in[0];
    const int*   esrc     = (const int*)d_in[1];
    const int*   edst     = (const int*)d_in[2];
    const float* ew       = (const float*)d_in[3];
    const float* W1       = (const float*)d_in[4];
    const float* b1       = (const float*)d_in[5];
    const float* gamma1   = (const float*)d_in[6];
    const float* beta1    = (const float*)d_in[7];
    const float* mean1    = (const float*)d_in[8];
    const float* var1     = (const float*)d_in[9];
    const float* W2       = (const float*)d_in[10];
    const float* b2       = (const float*)d_in[11];
    const float* prev     = (const float*)d_in[12];
    const int*   sens     = (const int*)d_in[13];
    const int*   ins      = (const int*)d_in[14];

    const int N = in_sizes[0] / F_IN;
    const int E = in_sizes[1];
    const int nb = (N + SCAN_CHUNK - 1) / SCAN_CHUNK;

    // ---- workspace layout (u32 words) ----
    u16* wt1   = (u16*)d_ws;                         // 128*128 u16 = 8192 u32
    u16* wt2   = wt1 + 128 * 128;                    // 64*128 u16  = 4096 u32
    u32* xw1b  = (u32*)d_ws + 12288;                 // N*64  (128 bf16 cols)
    u32* hb    = xw1b + (size_t)N * 64;              // N*64
    u32* xw2b  = hb + (size_t)N * 64;                // N*32
    u64* es_packed = (u64*)(xw2b + (size_t)N * 32);  // E x 8B (8B-aligned)
    float* scale = (float*)(es_packed + E);          // 128
    float* shift = scale + HID;                      // 128
    int* row_ptr = (int*)(shift + HID);              // N+1
    int* counts  = row_ptr + (N + 1);                // N
    int* bsums   = counts + N;                       // nb
    int* boffs   = bsums + nb;                       // nb
    u16* rank16  = (u16*)(boffs + nb);               // E u16

    float* out_lsm = (float*)d_out;
    float* out_emb = out_lsm + (size_t)N * CDIM;

    // ---- fused prep: weights + BN coeffs + counts zeroing ----
    prep_kernel<<<96, 256, 0, stream>>>(W1, W2, wt1, wt2, b1, gamma1, beta1,
                                        mean1, var1, scale, shift, counts, N);

    // ---- CSR build ----
    hist_kernel<<<(E + 255) / 256, 256, 0, stream>>>(edst, counts, rank16, E);
    scan_sums<<<nb, 256, 0, stream>>>(counts, bsums, N);
    scan_offsets<<<1, 64, 0, stream>>>(bsums, boffs, nb, row_ptr, N, E);
    scan_write<<<nb, 256, 0, stream>>>(counts, boffs, row_ptr, N);
    fill_kernel<<<2048, 256, 0, stream>>>(esrc, edst, ew, rank16, row_ptr,
                                          es_packed, E);

    // ---- layer 1 ----
    const int nt64 = (N + 63) / 64;
    gemm_xw1_mfma<<<nt64, 256, 0, stream>>>(features, wt1, xw1b, N);
    gather1_kernel<<<(N + 3) / 4, 256, 0, stream>>>(xw1b, row_ptr,
                                                    (const uint2*)es_packed,
                                                    scale, shift, hb, N);
    // ---- layer 2 ----
    gemm_xw2_mfma<<<nt64, 256, 0, stream>>>(hb, wt2, xw2b, N);
    gather2_final<<<(N + 3) / 4, 256, 0, stream>>>(xw2b, row_ptr,
                                                   (const uint2*)es_packed,
                                                   b2, prev, sens, ins,
                                                   out_lsm, out_emb, N);
}

// Round 22
// 419.072 us; speedup vs baseline: 1.3031x; 1.0398x over previous
//
#include <hip/hip_runtime.h>
#include <math.h>

#define F_IN 128
#define HID  128
#define CDIM 64
#define BN_EPS 1e-5f
#define SCAN_CHUNK 1024   // elements per scan block (256 thr x 4)

typedef unsigned int u32;
typedef unsigned short u16;
typedef unsigned long long u64;
typedef __attribute__((ext_vector_type(8))) short bf16x8;   // 8 bf16 = 4 VGPR
typedef __attribute__((ext_vector_type(4))) float f32x4;
typedef __attribute__((ext_vector_type(2))) float f32x2;

// bf16 helpers (RNE)
__device__ __forceinline__ float bf_lo(u32 p) {
    u32 x = p << 16; return __builtin_bit_cast(float, x);
}
__device__ __forceinline__ float bf_hi(u32 p) {
    u32 x = p & 0xffff0000u; return __builtin_bit_cast(float, x);
}
// unpack u32 (2 bf16) -> f32x2 {even col, odd col}
__device__ __forceinline__ f32x2 bf2(u32 p) {
    return (f32x2){bf_lo(p), bf_hi(p)};
}
__device__ __forceinline__ u16 f2bf(float f) {
    u32 x = __builtin_bit_cast(u32, f);
    return (u16)((x + 0x7fffu + ((x >> 16) & 1u)) >> 16);
}
__device__ __forceinline__ u32 pack2(float a, float b) {
    return (u32)f2bf(a) | ((u32)f2bf(b) << 16);   // lo = even col
}

// Swizzled LDS fragment load (G4 recipe, verified R10).
__device__ __forceinline__ bf16x8 frag_ld(const u16* lds, int row, int kb) {
    return *(const bf16x8*)&lds[row * 128 + (kb ^ ((row & 7) << 3))];
}

// ---------------------------------------------------------------------------
// prep_kernel: fuses wt_prep + bn_prep + counts-zeroing.
// ---------------------------------------------------------------------------
__global__ __launch_bounds__(256) void prep_kernel(
        const float* __restrict__ W1, const float* __restrict__ W2,
        u16* __restrict__ wt1, u16* __restrict__ wt2,
        const float* __restrict__ b1, const float* __restrict__ gamma,
        const float* __restrict__ beta, const float* __restrict__ mean,
        const float* __restrict__ var, float* __restrict__ scale,
        float* __restrict__ shift, int* __restrict__ counts, int N) {
    int t = blockIdx.x * 256 + threadIdx.x;
    if (t < 128 * 128) {
        int k = t >> 7, c = t & 127;
        wt1[c * 128 + (k ^ ((c & 7) << 3))] = f2bf(W1[t]);   // W1[k*128+c]
    } else if (t < 128 * 128 + 128 * 64) {
        int t2 = t - 128 * 128;
        int k = t2 >> 6, c = t2 & 63;
        wt2[c * 128 + (k ^ ((c & 7) << 3))] = f2bf(W2[t2]);  // W2[k*64+c]
    }
    if (t < HID) {
        float sc = gamma[t] * rsqrtf(var[t] + BN_EPS);
        scale[t] = sc;
        shift[t] = beta[t] + sc * (b1[t] - mean[t]);
    }
    for (int i = t; i < N; i += gridDim.x * 256) counts[i] = 0;
}

// ---------------------------------------------------------------------------
// GEMM1 (MFMA): Y[N,128](bf16) = X[N,128](fp32->bf16) @ W1.  (verified R10)
// ---------------------------------------------------------------------------
__global__ __launch_bounds__(256) void gemm_xw1_mfma(const float* __restrict__ X,
                                                     const u16* __restrict__ wt1,
                                                     u32* __restrict__ Yb, int N) {
    __shared__ u16 wl[128 * 128];   // 32 KB (swizzled Wt)
    __shared__ u16 xl[64 * 128];    // 16 KB (swizzled X tile, bf16)
    for (int i = threadIdx.x; i < 2048; i += 256)
        ((uint4*)wl)[i] = ((const uint4*)wt1)[i];
    const int l  = threadIdx.x & 63;
    const int wv = threadIdx.x >> 6;
    const int r16 = wv * 16;
    const int lr = l & 15;
    const int kq = l >> 4;
    const int ntiles = (N + 63) >> 6;
    for (int tile = blockIdx.x; tile < ntiles; tile += gridDim.x) {
        const int row0 = tile << 6;
        __syncthreads();
        for (int i = threadIdx.x; i < 2048; i += 256) {
            int r = i >> 5, c4 = i & 31;       // c4: float4 index (k = c4*4)
            int gr = row0 + r;
            float4 v = make_float4(0.f, 0.f, 0.f, 0.f);
            if (gr < N) v = *(const float4*)&X[(size_t)gr * F_IN + c4 * 4];
            uint2 p;
            p.x = pack2(v.x, v.y);
            p.y = pack2(v.z, v.w);
            *(uint2*)&xl[r * 128 + ((c4 * 4) ^ ((r & 7) << 3))] = p;
        }
        __syncthreads();
        f32x4 acc[8];
        #pragma unroll
        for (int c = 0; c < 8; ++c) acc[c] = (f32x4){0.f, 0.f, 0.f, 0.f};
        #pragma unroll
        for (int k0 = 0; k0 < 128; k0 += 32) {
            int kb = k0 + kq * 8;
            bf16x8 xf = frag_ld(xl, r16 + lr, kb);
            #pragma unroll
            for (int c = 0; c < 8; ++c) {
                bf16x8 wf = frag_ld(wl, c * 16 + lr, kb);
                acc[c] = __builtin_amdgcn_mfma_f32_16x16x32_bf16(wf, xf, acc[c], 0, 0, 0);
            }
        }
        int grow = row0 + r16 + lr;
        if (grow < N) {
            #pragma unroll
            for (int c = 0; c < 8; ++c) {
                uint2 o;
                o.x = pack2(acc[c][0], acc[c][1]);
                o.y = pack2(acc[c][2], acc[c][3]);
                *(uint2*)&Yb[(size_t)grow * 64 + c * 8 + kq * 2] = o;
            }
        }
    }
}

// ---------------------------------------------------------------------------
// GEMM2 (MFMA): Y[N,64](bf16) = H[N,128](bf16) @ W2.
// ---------------------------------------------------------------------------
__global__ __launch_bounds__(256) void gemm_xw2_mfma(const u32* __restrict__ Hb,
                                                     const u16* __restrict__ wt2,
                                                     u32* __restrict__ Yb, int N) {
    __shared__ u16 wl[64 * 128];    // 16 KB
    __shared__ u16 xl[64 * 128];    // 16 KB
    for (int i = threadIdx.x; i < 1024; i += 256)
        ((uint4*)wl)[i] = ((const uint4*)wt2)[i];
    const int l  = threadIdx.x & 63;
    const int wv = threadIdx.x >> 6;
    const int r16 = wv * 16;
    const int lr = l & 15;
    const int kq = l >> 4;
    const int ntiles = (N + 63) >> 6;
    for (int tile = blockIdx.x; tile < ntiles; tile += gridDim.x) {
        const int row0 = tile << 6;
        __syncthreads();
        for (int i = threadIdx.x; i < 1024; i += 256) {
            int r = i >> 4, c8 = i & 15;       // k = c8*8
            int gr = row0 + r;
            uint4 v = make_uint4(0u, 0u, 0u, 0u);
            if (gr < N) v = *(const uint4*)&Hb[(size_t)gr * 64 + c8 * 4];
            *(uint4*)&xl[r * 128 + ((c8 * 8) ^ ((r & 7) << 3))] = v;
        }
        __syncthreads();
        f32x4 acc[4];
        #pragma unroll
        for (int c = 0; c < 4; ++c) acc[c] = (f32x4){0.f, 0.f, 0.f, 0.f};
        #pragma unroll
        for (int k0 = 0; k0 < 128; k0 += 32) {
            int kb = k0 + kq * 8;
            bf16x8 xf = frag_ld(xl, r16 + lr, kb);
            #pragma unroll
            for (int c = 0; c < 4; ++c) {
                bf16x8 wf = frag_ld(wl, c * 16 + lr, kb);
                acc[c] = __builtin_amdgcn_mfma_f32_16x16x32_bf16(wf, xf, acc[c], 0, 0, 0);
            }
        }
        int grow = row0 + r16 + lr;
        if (grow < N) {
            #pragma unroll
            for (int c = 0; c < 4; ++c) {
                uint2 o;
                o.x = pack2(acc[c][0], acc[c][1]);
                o.y = pack2(acc[c][2], acc[c][3]);
                *(uint2*)&Yb[(size_t)grow * 32 + c * 8 + kq * 2] = o;
            }
        }
    }
}

// ---------------------------------------------------------------------------
// CSR build: hist (+rank) -> scan -> atomic-free fill  (verified R13)
// ---------------------------------------------------------------------------
__global__ __launch_bounds__(256) void hist_kernel(const int* __restrict__ dst,
                                                   int* __restrict__ counts,
                                                   u16* __restrict__ rank, int E) {
    int gid = blockIdx.x * 256 + threadIdx.x;
    int stride = gridDim.x * 256;
    for (; gid < E; gid += stride) {
        int d = __builtin_nontemporal_load(&dst[gid]);
        int r = atomicAdd(&counts[d], 1);
        __builtin_nontemporal_store((u16)r, &rank[gid]);
    }
}

__global__ __launch_bounds__(256) void scan_sums(const int* __restrict__ counts,
                                                 int* __restrict__ bsums, int N) {
    __shared__ int sdata[256];
    int base = blockIdx.x * SCAN_CHUNK + threadIdx.x * 4;
    int t = 0;
    #pragma unroll
    for (int j = 0; j < 4; ++j) { int i = base + j; if (i < N) t += counts[i]; }
    sdata[threadIdx.x] = t; __syncthreads();
    for (int off = 128; off > 0; off >>= 1) {
        if (threadIdx.x < off) sdata[threadIdx.x] += sdata[threadIdx.x + off];
        __syncthreads();
    }
    if (threadIdx.x == 0) bsums[blockIdx.x] = sdata[0];
}

__global__ void scan_offsets(const int* __restrict__ bsums, int* __restrict__ boffs,
                             int nb, int* __restrict__ row_ptr, int N, int E) {
    if (threadIdx.x == 0 && blockIdx.x == 0) {
        int run = 0;
        for (int i = 0; i < nb; ++i) { boffs[i] = run; run += bsums[i]; }
        row_ptr[N] = E;
    }
}

__global__ __launch_bounds__(256) void scan_write(const int* __restrict__ counts,
                                                  const int* __restrict__ boffs,
                                                  int* __restrict__ row_ptr, int N) {
    __shared__ int sdata[256];
    int base = blockIdx.x * SCAN_CHUNK + threadIdx.x * 4;
    int v[4]; int tsum = 0;
    #pragma unroll
    for (int j = 0; j < 4; ++j) {
        int i = base + j;
        v[j] = (i < N) ? counts[i] : 0;
        tsum += v[j];
    }
    sdata[threadIdx.x] = tsum; __syncthreads();
    for (int off = 1; off < 256; off <<= 1) {
        int t = (threadIdx.x >= off) ? sdata[threadIdx.x - off] : 0;
        __syncthreads();
        sdata[threadIdx.x] += t;
        __syncthreads();
    }
    int off0 = sdata[threadIdx.x] - tsum + boffs[blockIdx.x];
    #pragma unroll
    for (int j = 0; j < 4; ++j) {
        int i = base + j;
        if (i < N) { row_ptr[i] = off0; off0 += v[j]; }
    }
}

// ---------------------------------------------------------------------------
// fill: single pass, atomic-free. pos = row_ptr[d] + rank[gid].
// ---------------------------------------------------------------------------
__global__ __launch_bounds__(256) void fill_kernel(const int* __restrict__ src,
                                                   const int* __restrict__ dst,
                                                   const float* __restrict__ w,
                                                   const u16* __restrict__ rank,
                                                   const int* __restrict__ row_ptr,
                                                   u64* __restrict__ es_packed,
                                                   int E) {
    int gid = blockIdx.x * 256 + threadIdx.x;
    int stride = gridDim.x * 256;
    for (; gid < E; gid += stride) {
        int d = __builtin_nontemporal_load(&dst[gid]);
        int pos = row_ptr[d] + (int)__builtin_nontemporal_load(&rank[gid]);
        u64 lo = (u32)__builtin_nontemporal_load(&src[gid]);
        u64 hi = (u64)__builtin_bit_cast(u32, __builtin_nontemporal_load(&w[gid])) << 32;
        __builtin_nontemporal_store(lo | hi, &es_packed[pos]);
    }
}

// ---------------------------------------------------------------------------
// Gather layer 1 (D=128 bf16): one wave per dst row, 4 edges/iter
// (16 lanes/edge x uint4).
// ---------------------------------------------------------------------------
__global__ __launch_bounds__(256) void gather1_kernel(
        const u32* __restrict__ XWb, const int* __restrict__ row_ptr,
        const uint2* __restrict__ es, const float* __restrict__ scale,
        const float* __restrict__ shift, u32* __restrict__ Hb, int N) {
    int r = blockIdx.x * 4 + (threadIdx.x >> 6);
    if (r >= N) return;                     // wave-uniform
    int f = threadIdx.x & 63;
    int q = f >> 4;                         // edge within quad
    int fc = f & 15;                        // col group: bf16 cols 8fc..8fc+7
    int beg = row_ptr[r], end = row_ptr[r + 1];
    f32x2 A[4];
    #pragma unroll
    for (int j = 0; j < 4; ++j) A[j] = (f32x2){0.f, 0.f};
    for (int base = beg; base < end; base += 64) {
        int m = end - base; if (m > 64) m = 64;
        uint2 pk = (f < m) ? es[base + f] : make_uint2(0u, 0u);
        int   se = (int)pk.x;
        float we = __builtin_bit_cast(float, pk.y);
        for (int k = 0; k < m; k += 4) {
            int k0 = k + q;
            int   sk = __shfl(se, k0, 64);
            float wk = __shfl(we, k0, 64);
            f32x2 w2 = (f32x2){wk, wk};
            uint4 x = *(const uint4*)&XWb[(size_t)sk * 64 + 4 * fc];
            A[0] = __builtin_elementwise_fma(bf2(x.x), w2, A[0]);
            A[1] = __builtin_elementwise_fma(bf2(x.y), w2, A[1]);
            A[2] = __builtin_elementwise_fma(bf2(x.z), w2, A[2]);
            A[3] = __builtin_elementwise_fma(bf2(x.w), w2, A[3]);
        }
    }
    float acc[8] = {A[0][0], A[0][1], A[1][0], A[1][1],
                    A[2][0], A[2][1], A[3][0], A[3][1]};
    #pragma unroll
    for (int j = 0; j < 8; ++j) {
        acc[j] += __shfl_xor(acc[j], 16, 64);
        acc[j] += __shfl_xor(acc[j], 32, 64);
    }
    if (q == 0) {
        float4 sc0 = *(const float4*)&scale[8 * fc];
        float4 sc1 = *(const float4*)&scale[8 * fc + 4];
        float4 sh0 = *(const float4*)&shift[8 * fc];
        float4 sh1 = *(const float4*)&shift[8 * fc + 4];
        float h0 = fmaf(acc[0], sc0.x, sh0.x);
        float h1 = fmaf(acc[1], sc0.y, sh0.y);
        float h2 = fmaf(acc[2], sc0.z, sh0.z);
        float h3 = fmaf(acc[3], sc0.w, sh0.w);
        float h4 = fmaf(acc[4], sc1.x, sh1.x);
        float h5 = fmaf(acc[5], sc1.y, sh1.y);
        float h6 = fmaf(acc[6], sc1.z, sh1.z);
        float h7 = fmaf(acc[7], sc1.w, sh1.w);
        uint4 o;
        o.x = pack2(h0 > 0.f ? h0 : 0.f, h1 > 0.f ? h1 : 0.f);
        o.y = pack2(h2 > 0.f ? h2 : 0.f, h3 > 0.f ? h3 : 0.f);
        o.z = pack2(h4 > 0.f ? h4 : 0.f, h5 > 0.f ? h5 : 0.f);
        o.w = pack2(h6 > 0.f ? h6 : 0.f, h7 > 0.f ? h7 : 0.f);
        *(uint4*)&Hb[(size_t)r * 64 + 4 * fc] = o;
    }
}

// ---------------------------------------------------------------------------
// Gather layer 2 (D=64 bf16) + epilogue: ONE ROW PER 32-LANE HALF-WAVE
// (8 rows/block). 8 lanes/edge x uint4, 4 edges/iter; shfl width 32 keeps
// each row's edge broadcast inside its half-wave. Gains vs wave-per-row:
// es-load lane utilization 2x (deg~16 vs chunk 32), reduce 3->2 levels,
// and TWO independent row chains per wave for latency overlap.
// ---------------------------------------------------------------------------
__global__ __launch_bounds__(256) void gather2_final(
        const u32* __restrict__ XW2b, const int* __restrict__ row_ptr,
        const uint2* __restrict__ es, const float* __restrict__ b2,
        const float* __restrict__ prev, const int* __restrict__ sens,
        const int* __restrict__ ins, float* __restrict__ out_lsm,
        float* __restrict__ out_emb, int N) {
    int r = blockIdx.x * 8 + (threadIdx.x >> 5);
    if (r >= N) return;                     // half-wave-uniform
    int fl = threadIdx.x & 31;
    int q = fl >> 3;                        // edge within quad (0..3)
    int fc = fl & 7;                        // col group: bf16 cols 8fc..8fc+7
    int beg = row_ptr[r], end = row_ptr[r + 1];
    f32x2 A[4];
    #pragma unroll
    for (int j = 0; j < 4; ++j) A[j] = (f32x2){0.f, 0.f};
    for (int base = beg; base < end; base += 32) {
        int m = end - base; if (m > 32) m = 32;
        uint2 pk = (fl < m) ? es[base + fl] : make_uint2(0u, 0u);
        int   se = (int)pk.x;
        float we = __builtin_bit_cast(float, pk.y);
        for (int k = 0; k < m; k += 4) {
            int k0 = k + q;                 // k0 <= 31; lanes k0 >= m carry we=0
            int   sk = __shfl(se, k0, 32);
            float wk = __shfl(we, k0, 32);
            f32x2 w2 = (f32x2){wk, wk};
            uint4 x = *(const uint4*)&XW2b[(size_t)sk * 32 + 4 * fc];
            A[0] = __builtin_elementwise_fma(bf2(x.x), w2, A[0]);
            A[1] = __builtin_elementwise_fma(bf2(x.y), w2, A[1]);
            A[2] = __builtin_elementwise_fma(bf2(x.z), w2, A[2]);
            A[3] = __builtin_elementwise_fma(bf2(x.w), w2, A[3]);
        }
    }
    float a[8] = {A[0][0], A[0][1], A[1][0], A[1][1],
                  A[2][0], A[2][1], A[3][0], A[3][1]};
    #pragma unroll
    for (int j = 0; j < 8; ++j) {           // reduce over q (bits 3,4)
        a[j] += __shfl_xor(a[j], 8, 64);
        a[j] += __shfl_xor(a[j], 16, 64);
    }

    float4 bb0 = *(const float4*)&b2[8 * fc];
    float4 bb1 = *(const float4*)&b2[8 * fc + 4];
    float h[8];
    h[0] = a[0] + bb0.x; h[1] = a[1] + bb0.y;
    h[2] = a[2] + bb0.z; h[3] = a[3] + bb0.w;
    h[4] = a[4] + bb1.x; h[5] = a[5] + bb1.y;
    h[6] = a[6] + bb1.z; h[7] = a[7] + bb1.w;
    bool s_ = sens[r] != 0;
    bool i_ = ins[r] != 0;
    float4 pv0 = *(const float4*)&prev[(size_t)r * CDIM + 8 * fc];
    float4 pv1 = *(const float4*)&prev[(size_t)r * CDIM + 8 * fc + 4];
    float pvv[8] = {pv0.x, pv0.y, pv0.z, pv0.w, pv1.x, pv1.y, pv1.z, pv1.w};
    float o[8];
    #pragma unroll
    for (int j = 0; j < 8; ++j)
        o[j] = (s_ ? h[j] : pvv[j]) + (i_ ? h[j] : 0.f);
    // log-softmax over 64 cols: local max/sum of 8, reduce across fc lanes
    float mm = o[0];
    #pragma unroll
    for (int j = 1; j < 8; ++j) mm = fmaxf(mm, o[j]);
    #pragma unroll
    for (int off = 4; off > 0; off >>= 1) mm = fmaxf(mm, __shfl_xor(mm, off, 64));
    float s = 0.f;
    #pragma unroll
    for (int j = 0; j < 8; ++j) s += expf(o[j] - mm);
    #pragma unroll
    for (int off = 4; off > 0; off >>= 1) s += __shfl_xor(s, off, 64);
    float lse = mm + logf(s);
    if (q == 0) {
        *(float4*)&out_lsm[(size_t)r * CDIM + 8 * fc] =
            make_float4(o[0] - lse, o[1] - lse, o[2] - lse, o[3] - lse);
        *(float4*)&out_lsm[(size_t)r * CDIM + 8 * fc + 4] =
            make_float4(o[4] - lse, o[5] - lse, o[6] - lse, o[7] - lse);
        *(float4*)&out_emb[(size_t)r * CDIM + 8 * fc] =
            make_float4(o[0], o[1], o[2], o[3]);
        *(float4*)&out_emb[(size_t)r * CDIM + 8 * fc + 4] =
            make_float4(o[4], o[5], o[6], o[7]);
    }
}

extern "C" void kernel_launch(void* const* d_in, const int* in_sizes, int n_in,
                              void* d_out, int out_size, void* d_ws, size_t ws_size,
                              hipStream_t stream) {
    const float* features = (const float*)d_in[0];
    const int*   esrc     = (const int*)d_in[1];
    const int*   edst     = (const int*)d_in[2];
    const float* ew       = (const float*)d_in[3];
    const float* W1       = (const float*)d_in[4];
    const float* b1       = (const float*)d_in[5];
    const float* gamma1   = (const float*)d_in[6];
    const float* beta1    = (const float*)d_in[7];
    const float* mean1    = (const float*)d_in[8];
    const float* var1     = (const float*)d_in[9];
    const float* W2       = (const float*)d_in[10];
    const float* b2       = (const float*)d_in[11];
    const float* prev     = (const float*)d_in[12];
    const int*   sens     = (const int*)d_in[13];
    const int*   ins      = (const int*)d_in[14];

    const int N = in_sizes[0] / F_IN;
    const int E = in_sizes[1];
    const int nb = (N + SCAN_CHUNK - 1) / SCAN_CHUNK;

    // ---- workspace layout (u32 words) ----
    u16* wt1   = (u16*)d_ws;                         // 128*128 u16 = 8192 u32
    u16* wt2   = wt1 + 128 * 128;                    // 64*128 u16  = 4096 u32
    u32* xw1b  = (u32*)d_ws + 12288;                 // N*64  (128 bf16 cols)
    u32* hb    = xw1b + (size_t)N * 64;              // N*64
    u32* xw2b  = hb + (size_t)N * 64;                // N*32
    u64* es_packed = (u64*)(xw2b + (size_t)N * 32);  // E x 8B (8B-aligned)
    float* scale = (float*)(es_packed + E);          // 128
    float* shift = scale + HID;                      // 128
    int* row_ptr = (int*)(shift + HID);              // N+1
    int* counts  = row_ptr + (N + 1);                // N
    int* bsums   = counts + N;                       // nb
    int* boffs   = bsums + nb;                       // nb
    u16* rank16  = (u16*)(boffs + nb);               // E u16

    float* out_lsm = (float*)d_out;
    float* out_emb = out_lsm + (size_t)N * CDIM;

    // ---- fused prep: weights + BN coeffs + counts zeroing ----
    prep_kernel<<<96, 256, 0, stream>>>(W1, W2, wt1, wt2, b1, gamma1, beta1,
                                        mean1, var1, scale, shift, counts, N);

    // ---- CSR build ----
    hist_kernel<<<(E + 255) / 256, 256, 0, stream>>>(edst, counts, rank16, E);
    scan_sums<<<nb, 256, 0, stream>>>(counts, bsums, N);
    scan_offsets<<<1, 64, 0, stream>>>(bsums, boffs, nb, row_ptr, N, E);
    scan_write<<<nb, 256, 0, stream>>>(counts, boffs, row_ptr, N);
    fill_kernel<<<2048, 256, 0, stream>>>(esrc, edst, ew, rank16, row_ptr,
                                          es_packed, E);

    // ---- layer 1 ----
    const int nt64 = (N + 63) / 64;
    gemm_xw1_mfma<<<nt64, 256, 0, stream>>>(features, wt1, xw1b, N);
    gather1_kernel<<<(N + 3) / 4, 256, 0, stream>>>(xw1b, row_ptr,
                                                    (const uint2*)es_packed,
                                                    scale, shift, hb, N);
    // ---- layer 2 ----
    gemm_xw2_mfma<<<nt64, 256, 0, stream>>>(hb, wt2, xw2b, N);
    gather2_final<<<(N + 7) / 8, 256, 0, stream>>>(xw2b, row_ptr,
                                                   (const uint2*)es_packed,
                                                   b2, prev, sens, ins,
                                                   out_lsm, out_emb, N);
}